// Round 3
// baseline (8301.390 us; speedup 1.0000x reference)
//
#include <hip/hip_runtime.h>
#include <hip/hip_bf16.h>
#include <math.h>

#define D_IN 56
#define H    501
#define T_STEPS 277
#define O_OUT 76
#define BATCH 256
#define HP   512    // padded K (hidden) for MFMA
#define NP   1504   // padded 3H
#define SSTR 520    // LDS staging row stride in shorts (1040B, 16B-aligned)
#define HSTR 576    // hgl slot size in floats (32 rows * 18)
#define NSLOT 15    // 5 groups x 3 gates, ds_add-accumulated

// dynamic LDS layout: SA | SB | SC | hgl[15][576] | sg0[32*48] | sb[3*4*16]
#define LDS_SA    0
#define LDS_SB    (32 * SSTR)
#define LDS_SC    (64 * SSTR)
#define LDS_STAGE (96 * SSTR)                 // 99,840 B staging (shorts)
#define DYN_LDS   (96 * SSTR * 2 + NSLOT * HSTR * 4 + 32 * 48 * 4 + 3 * 4 * 16 * 4)  // 141,312

typedef __attribute__((ext_vector_type(8))) short s16x8;
typedef __attribute__((ext_vector_type(4))) float f32x4;
typedef unsigned long long ull;

__device__ __forceinline__ short f2bf(float x) {
    union { float f; unsigned u; } v; v.f = x;
    unsigned r = (v.u + 0x7fffu + ((v.u >> 16) & 1u)) >> 16;
    return (short)r;
}
__device__ __forceinline__ float bf2f(short b) {
    union { unsigned u; float f; } v; v.u = ((unsigned)(unsigned short)b) << 16;
    return v.f;
}
__device__ __forceinline__ float sigm(float x) { return 1.f / (1.f + __expf(-x)); }
__device__ __forceinline__ float tanh_fast(float x) { return 1.f - 2.f / (1.f + __expf(2.f * x)); }

// direct global->LDS DMA, 16B per lane; LDS dest is wave-uniform base + lane*16
__device__ __forceinline__ void glds16(const void* g, void* l) {
    __builtin_amdgcn_global_load_lds((const __attribute__((address_space(1))) unsigned int*)g,
                                     (__attribute__((address_space(3))) unsigned int*)l,
                                     16, 0, 0);
}

// ---------------------------------------------------------------------------
// Weight packing (unchanged, proven correct)
// ---------------------------------------------------------------------------
__global__ void k_pack_gru(const float* __restrict__ w_ih,
                           const float* __restrict__ w_hh,
                           short* __restrict__ dst, int KT) {
    int tile = blockIdx.x;
    int ktp  = tile % KT;
    int g    = (tile / KT) % 3;
    int j    = tile / (KT * 3);
    int l    = threadIdx.x;
    int u    = j * 16 + (l & 15);
    int row  = g * H + u;
    const float* src; int k0;
    if (KT == 32) {
        if (ktp < 16) { src = w_ih; k0 = ktp * 32; }
        else          { src = w_hh; k0 = (ktp - 16) * 32; }
    } else          { src = w_hh; k0 = ktp * 32; }
    k0 += (l >> 4) * 8;
    short* p = dst + ((size_t)tile * 64 + l) * 8;
    for (int jj = 0; jj < 8; jj++) {
        int k = k0 + jj;
        float v = 0.f;
        if (u < H && k < H) v = src[(size_t)row * H + k];
        p[jj] = f2bf(v);
    }
}

__global__ void k_pack_fc2(const float* __restrict__ w, short* __restrict__ dst) {
    int tile = blockIdx.x;
    int kt = tile % 16, mt = tile / 16;
    int l = threadIdx.x;
    int o = mt * 16 + (l & 15);
    int k0 = kt * 32 + (l >> 4) * 8;
    short* p = dst + ((size_t)tile * 64 + l) * 8;
    for (int jj = 0; jj < 8; jj++) {
        int k = k0 + jj; float v = 0.f;
        if (o < O_OUT && k < H) v = w[(size_t)o * H + k];
        p[jj] = f2bf(v);
    }
}

__global__ void k_hin(const float* __restrict__ x, const float* __restrict__ w,
                      const float* __restrict__ bias, float* __restrict__ hin) {
    int b = blockIdx.x, o = threadIdx.x;
    float acc = 0.f;
    if (o < D_IN) {
        acc = bias[o];
        for (int k = 0; k < D_IN; k++) acc += x[b * D_IN + k] * w[o * D_IN + k];
        acc = fmaxf(acc, 0.f);
    }
    hin[b * 64 + o] = (o < D_IN) ? acc : 0.f;
}

__global__ void k_g0(const float* __restrict__ hin, const float* __restrict__ w_ih0,
                     const float* __restrict__ b_ih0, float* __restrict__ g0) {
    int b = blockIdx.x, tid = threadIdx.x;
    __shared__ float shx[D_IN];
    if (tid < D_IN) shx[tid] = hin[b * 64 + tid];
    __syncthreads();
    for (int o = tid; o < NP; o += 256) {
        float acc = 0.f;
        if (o < 3 * H) {
            acc = b_ih0[o];
            for (int k = 0; k < D_IN; k++) acc += shx[k] * w_ih0[(size_t)o * D_IN + k];
        }
        g0[(size_t)b * NP + o] = acc;
    }
}

// ---------------------------------------------------------------------------
// Register-pinned weight preload for one segment (LEN k-tiles x 3 gates).
// volatile => loads execute exactly once; values must live in VGPRs.
// ---------------------------------------------------------------------------
template <int LEN>
__device__ __forceinline__ void preload_w(s16x8* dst, const short* wpk, int KT,
                                          int jj3, int ktA, int lane) {
    #pragma unroll
    for (int g = 0; g < 3; g++) {
        const volatile s16x8* vp =
            (const volatile s16x8*)(wpk + ((size_t)((jj3 + g) * KT + ktA) * 512));
        #pragma unroll
        for (int kk = 0; kk < LEN; kk++) dst[3 * kk + g] = vp[kk * 64 + lane];
    }
}

// ---------------------------------------------------------------------------
// One phase-B segment: NK k-tiles against one A tile, 3 gates, results
// ds_add-accumulated into hgl slots [slotbase .. slotbase+2].
// ---------------------------------------------------------------------------
template <int NK>
__device__ __forceinline__ void role_seg(const short* __restrict__ stg, int abase, int ak0,
                                         const s16x8* __restrict__ wv,
                                         float* __restrict__ hgl, int slotbase, int lane) {
    const int arow = lane & 15;
    const int acol = (lane >> 4) * 8;
    f32x4 a0[3], a1[3];
    #pragma unroll
    for (int g = 0; g < 3; g++) { a0[g] = (f32x4){0.f,0.f,0.f,0.f}; a1[g] = (f32x4){0.f,0.f,0.f,0.f}; }
    #pragma unroll
    for (int kk = 0; kk < NK; kk++) {
        int ak = ak0 + kk;
        s16x8 x0 = *(const s16x8*)&stg[abase + arow * SSTR + ak * 32 + acol];
        s16x8 x1 = *(const s16x8*)&stg[abase + (16 + arow) * SSTR + ak * 32 + acol];
        #pragma unroll
        for (int g = 0; g < 3; g++) {
            a0[g] = __builtin_amdgcn_mfma_f32_16x16x32_bf16(x0, wv[3 * kk + g], a0[g], 0, 0, 0);
            a1[g] = __builtin_amdgcn_mfma_f32_16x16x32_bf16(x1, wv[3 * kk + g], a1[g], 0, 0, 0);
        }
    }
    const int ul = lane & 15, mrow = (lane >> 4) * 4;
    #pragma unroll
    for (int g = 0; g < 3; g++) {
        float* base = hgl + (size_t)(slotbase + g) * HSTR;
        #pragma unroll
        for (int r = 0; r < 4; r++) {
            atomicAdd(&base[(mrow + r) * 18 + ul],      a0[g][r]);
            atomicAdd(&base[(16 + mrow + r) * 18 + ul], a1[g][r]);
        }
    }
}

// ---------------------------------------------------------------------------
// Persistent pipelined GRU — R12: 8 waves (512 thr), even NK=10 weight split
// so every wave pins only 30 s16x8 = 120 VGPRs of weights (true register
// residency; R2's 6-wave split needed 192 and spilled). Partial gate sums
// accumulate via ds_add_f32 into 15 slots; phase C reads + zeroes them.
// Groups (16 kt each): G0=L0hh(A=SA) G1=L1ih(SA) G2=L1hh(SB) G3=L2ih(SB)
// G4=L2hh(SC). Wave w owns kt-window [10w,10w+10) of the 80-kt concat.
// Also fixes needB (SB is read by L2-ih at s=T+1).
// ---------------------------------------------------------------------------
__global__ __launch_bounds__(512, 2)   // 2 waves/EU => 256 VGPR cap; 1 block/CU (LDS)
void k_gru_persist(const short* __restrict__ packW0,
                   const short* __restrict__ packW1,
                   const short* __restrict__ packW2,
                   const float* __restrict__ g0,
                   const float* __restrict__ b_hh0,
                   const float* __restrict__ b_ih1, const float* __restrict__ b_hh1,
                   const float* __restrict__ b_ih2, const float* __restrict__ b_hh2,
                   short* __restrict__ ysA,    // layer0 out at t, overwritten by layer2 at t (step t+2)
                   short* __restrict__ ysB,    // layer1 out
                   unsigned* __restrict__ cnt) {
    const int bg   = blockIdx.x & 7;      // XCD-local batch group (dispatch round-robins XCDs)
    const int j    = blockIdx.x >> 3;     // j-slice 0..31 within the XCD
    const int b0   = bg * 32;
    const int tid  = threadIdx.x;
    const int lane = tid & 63;
    const int wave = tid >> 6;
    const s16x8 z8 = {0, 0, 0, 0, 0, 0, 0, 0};

    extern __shared__ __align__(16) char smem[];
    short* stg = (short*)smem;                         // SA/SB/SC
    float* hgl = (float*)(smem + LDS_STAGE * 2);       // [NSLOT][HSTR]
    float* sg0 = hgl + NSLOT * HSTR;                   // [32*48]
    float* sbb = sg0 + 32 * 48;                        // [3][4][16]

    // ---- register-pinned weights: 30 s16x8 per lane (120 VGPR)
    s16x8 wv[30];
    {
        const int jj3 = j * 3;
        switch (wave) {
            case 0: preload_w<10>(wv,      packW0, 16, jj3, 0,      lane); break;
            case 1: preload_w<6> (wv,      packW0, 16, jj3, 10,     lane);
                    preload_w<4> (wv + 18, packW1, 32, jj3, 0,      lane); break;
            case 2: preload_w<10>(wv,      packW1, 32, jj3, 4,      lane); break;
            case 3: preload_w<2> (wv,      packW1, 32, jj3, 14,     lane);
                    preload_w<8> (wv + 6,  packW1, 32, jj3, 16 + 0, lane); break;
            case 4: preload_w<8> (wv,      packW1, 32, jj3, 16 + 8, lane);
                    preload_w<2> (wv + 24, packW2, 32, jj3, 0,      lane); break;
            case 5: preload_w<10>(wv,      packW2, 32, jj3, 2,      lane); break;
            case 6: preload_w<4> (wv,      packW2, 32, jj3, 12,     lane);
                    preload_w<6> (wv + 12, packW2, 32, jj3, 16 + 0, lane); break;
            default: preload_w<10>(wv,     packW2, 32, jj3, 16 + 6, lane); break;
        }
    }

    // ---- init LDS: hgl zeros, layer0 x-gate constants, bias table
    for (int c = tid; c < NSLOT * HSTR; c += 512) hgl[c] = 0.f;
    for (int c = tid; c < 32 * 48; c += 512) {
        int m = c / 48, col = c % 48;
        int g = col >> 4, ul = col & 15;
        int u = j * 16 + ul;
        float v = 0.f;
        if (u < H) {
            v = g0[(size_t)(b0 + m) * NP + g * H + u];
            if (g == 0) v += b_hh0[u];
            else if (g == 1) v += b_hh0[H + u];
        }
        sg0[m * 48 + col] = v;
    }
    if (tid < 48) {
        int l = tid >> 4, ul = tid & 15, u = j * 16 + ul;
        float br = 0.f, bz = 0.f, bxn = 0.f, bhn = 0.f;
        if (u < H) {
            if (l == 0) bhn = b_hh0[2 * H + u];
            else {
                const float* bi = (l == 1) ? b_ih1 : b_ih2;
                const float* bh = (l == 1) ? b_hh1 : b_hh2;
                br = bi[u] + bh[u]; bz = bi[H + u] + bh[H + u];
                bxn = bi[2 * H + u]; bhn = bh[2 * H + u];
            }
        }
        sbb[(l * 4 + 0) * 16 + ul] = br;  sbb[(l * 4 + 1) * 16 + ul] = bz;
        sbb[(l * 4 + 2) * 16 + ul] = bxn; sbb[(l * 4 + 3) * 16 + ul] = bhn;
    }
    __syncthreads();

    unsigned* myflags = cnt + bg * 32;   // 32 flags in one 128B line per bg

    for (int s = 0; s < T_STEPS + 2; ++s) {
        const bool hasL0 = (s < T_STEPS);
        const bool hasL1 = (s >= 1 && s <= T_STEPS);
        const bool hasL2 = (s >= 2);
        const short* ysAm1 = ysA + (size_t)(s - 1) * BATCH * HP;
        const short* ysBm2 = ysB + (size_t)(s - 2) * BATCH * HP;
        const short* ysAm3 = ysA + (size_t)(s - 3) * BATCH * HP;

        // ================= PHASE A: staging (DMA for SA/SB, atomic for SC) ==
        {
            const bool needA = (s <= T_STEPS);          // SA: L0 hold + L1-ih input
            const bool ldA   = (s >= 1) && needA;
            const bool needB = (s >= 1);                // SB: L1-hh/hold AND L2-ih input
            const bool ldB   = (s >= 2) && needB;
            const bool needC = hasL2;                   // SC: L2-hh + L2 hold
            const bool ldC   = (s >= 3);
            #pragma unroll
            for (int i = 0; i < 4; i++) {
                int r = wave * 4 + i;
                size_t go = (size_t)(b0 + r) * HP + (size_t)lane * 8;
                if (ldA)        glds16(ysAm1 + go, &stg[LDS_SA + r * SSTR]);
                else if (needA) *(s16x8*)&stg[LDS_SA + r * SSTR + lane * 8] = z8;
                if (ldB)        glds16(ysBm2 + go, &stg[LDS_SB + r * SSTR]);
                else if (needB) *(s16x8*)&stg[LDS_SB + r * SSTR + lane * 8] = z8;
                if (ldC) {
                    const ull* pc = (const ull*)(ysAm3 + go);
                    union { ull q[2]; s16x8 v; } uu;
                    uu.q[0] = __hip_atomic_load(pc,     __ATOMIC_RELAXED, __HIP_MEMORY_SCOPE_AGENT);
                    uu.q[1] = __hip_atomic_load(pc + 1, __ATOMIC_RELAXED, __HIP_MEMORY_SCOPE_AGENT);
                    *(s16x8*)&stg[LDS_SC + r * SSTR + lane * 8] = uu.v;
                } else if (needC) {
                    *(s16x8*)&stg[LDS_SC + r * SSTR + lane * 8] = z8;
                }
            }
        }
        asm volatile("s_waitcnt vmcnt(0)" ::: "memory"); // DMA writes landed in LDS
        __syncthreads();                                   // (1) tiles staged

        // ================= PHASE B: 8 waves x NK=10, register B-operands ====
        switch (wave) {
            case 0: if (hasL0) role_seg<10>(stg, LDS_SA, 0,  wv,      hgl, 0,  lane); break;
            case 1: if (hasL0) role_seg<6> (stg, LDS_SA, 10, wv,      hgl, 0,  lane);
                    if (hasL1) role_seg<4> (stg, LDS_SA, 0,  wv + 18, hgl, 3,  lane); break;
            case 2: if (hasL1) role_seg<10>(stg, LDS_SA, 4,  wv,      hgl, 3,  lane); break;
            case 3: if (hasL1) role_seg<2> (stg, LDS_SA, 14, wv,      hgl, 3,  lane);
                    if (hasL1) role_seg<8> (stg, LDS_SB, 0,  wv + 6,  hgl, 6,  lane); break;
            case 4: if (hasL1) role_seg<8> (stg, LDS_SB, 8,  wv,      hgl, 6,  lane);
                    if (hasL2) role_seg<2> (stg, LDS_SB, 0,  wv + 24, hgl, 9,  lane); break;
            case 5: if (hasL2) role_seg<10>(stg, LDS_SB, 2,  wv,      hgl, 9,  lane); break;
            case 6: if (hasL2) role_seg<4> (stg, LDS_SB, 12, wv,      hgl, 9,  lane);
                    if (hasL2) role_seg<6> (stg, LDS_SC, 0,  wv + 12, hgl, 12, lane); break;
            default: if (hasL2) role_seg<10>(stg, LDS_SC, 6, wv,      hgl, 12, lane); break;
        }
        __syncthreads();                                   // (2) hgl complete

        // ================= PHASE C: all gates (768 items / 512 threads) =====
        #pragma unroll
        for (int it = 0; it < 2; it++) {
            int idx = tid + it * 512;
            int which = idx >> 8, id8 = idx & 255;
            int m = id8 >> 3, pr = id8 & 7;
            int b = b0 + m;
            if (which == 0 && hasL0) {
                short* dst = ysA + (size_t)s * BATCH * HP;
                unsigned pk = 0;
                #pragma unroll
                for (int e = 0; e < 2; e++) {
                    int ul = pr * 2 + e, u = j * 16 + ul, mo = m * 18 + ul;
                    float hv = 0.f;
                    if (u < H) {
                        float hr = hgl[0 * HSTR + mo];
                        float hz = hgl[1 * HSTR + mo];
                        float hn = hgl[2 * HSTR + mo];
                        hgl[0 * HSTR + mo] = 0.f; hgl[1 * HSTR + mo] = 0.f; hgl[2 * HSTR + mo] = 0.f;
                        float r = sigm(sg0[m * 48 + ul] + hr);
                        float z = sigm(sg0[m * 48 + 16 + ul] + hz);
                        float n = tanh_fast(sg0[m * 48 + 32 + ul] + r * (hn + sbb[3 * 16 + ul]));
                        float hold = bf2f(stg[LDS_SA + m * SSTR + u]);
                        hv = (1.f - z) * n + z * hold;
                    }
                    pk |= ((unsigned)(unsigned short)f2bf(hv)) << (16 * e);
                }
                __hip_atomic_store((unsigned*)&dst[(size_t)b * HP + j * 16 + pr * 2], pk,
                                   __ATOMIC_RELAXED, __HIP_MEMORY_SCOPE_AGENT);
            } else if (which == 1 && hasL1) {
                short* dst = ysB + (size_t)(s - 1) * BATCH * HP;
                unsigned pk = 0;
                #pragma unroll
                for (int e = 0; e < 2; e++) {
                    int ul = pr * 2 + e, u = j * 16 + ul, mo = m * 18 + ul;
                    float hv = 0.f;
                    if (u < H) {
                        float xr = hgl[3 * HSTR + mo] + sbb[(4 + 0) * 16 + ul];
                        float xz = hgl[4 * HSTR + mo] + sbb[(4 + 1) * 16 + ul];
                        float xn = hgl[5 * HSTR + mo] + sbb[(4 + 2) * 16 + ul];
                        float hr = hgl[6 * HSTR + mo];
                        float hz = hgl[7 * HSTR + mo];
                        float hn = hgl[8 * HSTR + mo] + sbb[(4 + 3) * 16 + ul];
                        hgl[3 * HSTR + mo] = 0.f; hgl[4 * HSTR + mo] = 0.f; hgl[5 * HSTR + mo] = 0.f;
                        hgl[6 * HSTR + mo] = 0.f; hgl[7 * HSTR + mo] = 0.f; hgl[8 * HSTR + mo] = 0.f;
                        float r = sigm(xr + hr);
                        float z = sigm(xz + hz);
                        float n = tanh_fast(xn + r * hn);
                        float hold = bf2f(stg[LDS_SB + m * SSTR + u]);
                        hv = (1.f - z) * n + z * hold;
                    }
                    pk |= ((unsigned)(unsigned short)f2bf(hv)) << (16 * e);
                }
                __hip_atomic_store((unsigned*)&dst[(size_t)b * HP + j * 16 + pr * 2], pk,
                                   __ATOMIC_RELAXED, __HIP_MEMORY_SCOPE_AGENT);
            } else if (which == 2 && hasL2) {
                short* dst = ysA + (size_t)(s - 2) * BATCH * HP;
                unsigned pk = 0;
                #pragma unroll
                for (int e = 0; e < 2; e++) {
                    int ul = pr * 2 + e, u = j * 16 + ul, mo = m * 18 + ul;
                    float hv = 0.f;
                    if (u < H) {
                        float xr = hgl[9  * HSTR + mo] + sbb[(8 + 0) * 16 + ul];
                        float xz = hgl[10 * HSTR + mo] + sbb[(8 + 1) * 16 + ul];
                        float xn = hgl[11 * HSTR + mo] + sbb[(8 + 2) * 16 + ul];
                        float hr = hgl[12 * HSTR + mo];
                        float hz = hgl[13 * HSTR + mo];
                        float hn = hgl[14 * HSTR + mo] + sbb[(8 + 3) * 16 + ul];
                        hgl[9  * HSTR + mo] = 0.f; hgl[10 * HSTR + mo] = 0.f; hgl[11 * HSTR + mo] = 0.f;
                        hgl[12 * HSTR + mo] = 0.f; hgl[13 * HSTR + mo] = 0.f; hgl[14 * HSTR + mo] = 0.f;
                        float r = sigm(xr + hr);
                        float z = sigm(xz + hz);
                        float n = tanh_fast(xn + r * hn);
                        float hold = bf2f(stg[LDS_SC + m * SSTR + u]);
                        hv = (1.f - z) * n + z * hold;
                    }
                    pk |= ((unsigned)(unsigned short)f2bf(hv)) << (16 * e);
                }
                __hip_atomic_store((unsigned*)&dst[(size_t)b * HP + j * 16 + pr * 2], pk,
                                   __ATOMIC_RELAXED, __HIP_MEMORY_SCOPE_AGENT);
            }
        }
        __syncthreads();    // (3) stores + hgl zeroing complete

        // ---- per-bg 32-block barrier: flag store + 32-lane vector poll
        if (tid == 0) {
            asm volatile("s_waitcnt vmcnt(0)" ::: "memory");
            __hip_atomic_store(myflags + j, (unsigned)(s + 1),
                               __ATOMIC_RELAXED, __HIP_MEMORY_SCOPE_AGENT);
        }
        if (tid < 32) {
            const unsigned tgt = (unsigned)(s + 1);
            unsigned* fl = myflags + tid;
            for (;;) {
                unsigned v = __hip_atomic_load(fl, __ATOMIC_RELAXED, __HIP_MEMORY_SCOPE_AGENT);
                if (__all(v >= tgt)) break;
            }
        }
        __syncthreads();                                   // (4)
    }
}

// ---------------------------------------------------------------------------
// fc2 + transpose (reads ysA = layer2 output; fresh kernel => coherent)
// ---------------------------------------------------------------------------
__global__ __launch_bounds__(256, 1)
void k_fc2(const short* __restrict__ ys2, const short* __restrict__ fc2p,
           const float* __restrict__ fc2_b, float* __restrict__ out) {
    int b = blockIdx.x;
    int tid = threadIdx.x, lane = tid & 63, wave = tid >> 6;
    const s16x8 zf = {0, 0, 0, 0, 0, 0, 0, 0};
    for (int ntile = wave; ntile < 18; ntile += 4) {
        int tt = ntile * 16 + (lane & 15);
        s16x8 bf[16];
        for (int kt = 0; kt < 16; kt++) {
            if (tt < T_STEPS)
                bf[kt] = *(const s16x8*)&ys2[((size_t)tt * BATCH + b) * HP + kt * 32 + (lane >> 4) * 8];
            else
                bf[kt] = zf;
        }
        for (int mt = 0; mt < 5; mt++) {
            f32x4 acc = {0.f, 0.f, 0.f, 0.f};
            for (int kt = 0; kt < 16; kt++) {
                s16x8 af = *(const s16x8*)&fc2p[(((size_t)mt * 16 + kt) * 64 + lane) * 8];
                acc = __builtin_amdgcn_mfma_f32_16x16x32_bf16(af, bf[kt], acc, 0, 0, 0);
            }
            int obase = mt * 16 + (lane >> 4) * 4;
            for (int r = 0; r < 4; r++) {
                int o = obase + r;
                if (o < O_OUT && tt < T_STEPS)
                    out[((size_t)b * O_OUT + o) * T_STEPS + tt] = acc[r] + fc2_b[o];
            }
        }
    }
}

// ---------------------------------------------------------------------------
extern "C" void kernel_launch(void* const* d_in, const int* in_sizes, int n_in,
                              void* d_out, int out_size, void* d_ws, size_t ws_size,
                              hipStream_t stream) {
    const float* x     = (const float*)d_in[0];
    const float* fc1_w = (const float*)d_in[1];
    const float* fc1_b = (const float*)d_in[2];
    const float* w_ih0 = (const float*)d_in[3];
    const float* w_hh0 = (const float*)d_in[4];
    const float* b_ih0 = (const float*)d_in[5];
    const float* b_hh0 = (const float*)d_in[6];
    const float* w_ih1 = (const float*)d_in[7];
    const float* w_hh1 = (const float*)d_in[8];
    const float* b_ih1 = (const float*)d_in[9];
    const float* b_hh1 = (const float*)d_in[10];
    const float* w_ih2 = (const float*)d_in[11];
    const float* w_hh2 = (const float*)d_in[12];
    const float* b_ih2 = (const float*)d_in[13];
    const float* b_hh2 = (const float*)d_in[14];
    const float* fc2_w = (const float*)d_in[15];
    const float* fc2_b = (const float*)d_in[16];
    float* out = (float*)d_out;

    char* p = (char*)d_ws;
    auto alloc = [&](size_t bytes) {
        char* r = p; p += (bytes + 255) & ~(size_t)255; return r;
    };
    short* packW0 = (short*)alloc((size_t)32 * 3 * 16 * 64 * 8 * 2);
    short* packW1 = (short*)alloc((size_t)32 * 3 * 32 * 64 * 8 * 2);
    short* packW2 = (short*)alloc((size_t)32 * 3 * 32 * 64 * 8 * 2);
    short* packF  = (short*)alloc((size_t)80 * 64 * 8 * 2);
    float* hin    = (float*)alloc((size_t)BATCH * 64 * 4);
    float* g0     = (float*)alloc((size_t)BATCH * NP * 4);
    unsigned* cnt = (unsigned*)alloc(256 * 4);
    short* ysA    = (short*)alloc((size_t)T_STEPS * BATCH * HP * 2);
    short* ysB    = (short*)alloc((size_t)T_STEPS * BATCH * HP * 2);

    // opt in to >64KB dynamic LDS (host-side attribute; graph-capture safe)
    static bool attr_set = false;
    if (!attr_set) {
        (void)hipFuncSetAttribute((const void*)k_gru_persist,
                                  hipFuncAttributeMaxDynamicSharedMemorySize,
                                  DYN_LDS);
        attr_set = true;
    }

    hipMemsetAsync(cnt, 0, 256 * 4, stream);
    k_pack_gru<<<32 * 3 * 16, 64, 0, stream>>>(nullptr, w_hh0, packW0, 16);
    k_pack_gru<<<32 * 3 * 32, 64, 0, stream>>>(w_ih1, w_hh1, packW1, 32);
    k_pack_gru<<<32 * 3 * 32, 64, 0, stream>>>(w_ih2, w_hh2, packW2, 32);
    k_pack_fc2<<<80, 64, 0, stream>>>(fc2_w, packF);
    k_hin<<<BATCH, 64, 0, stream>>>(x, fc1_w, fc1_b, hin);
    k_g0<<<BATCH, 256, 0, stream>>>(hin, w_ih0, b_ih0, g0);

    k_gru_persist<<<256, 512, DYN_LDS, stream>>>(packW0, packW1, packW2, g0,
                                                 b_hh0, b_ih1, b_hh1, b_ih2, b_hh2,
                                                 ysA, ysB, cnt);

    k_fc2<<<BATCH, 256, 0, stream>>>(ysA, packF, fc2_b, out);
}

// Round 4
// 5863.021 us; speedup vs baseline: 1.4159x; 1.4159x over previous
//
#include <hip/hip_runtime.h>
#include <hip/hip_bf16.h>
#include <math.h>

#define D_IN 56
#define H    501
#define T_STEPS 277
#define O_OUT 76
#define BATCH 256
#define HP   512    // padded K (hidden) for MFMA
#define NP   1504   // padded 3H
#define SSTR 520    // LDS staging row stride in shorts (1040B, 16B-aligned)
#define HSTR 576    // hgl slot size in floats (32 rows * 18)

// dynamic LDS layout: SA | SB | SC | hgl[18][576] | sg0[32*48] | sb[3*4*16]
#define LDS_SA    0
#define LDS_SB    (32 * SSTR)
#define LDS_SC    (64 * SSTR)
#define LDS_STAGE (96 * SSTR)                 // 99,840 B staging (shorts)
#define DYN_LDS   (96 * SSTR * 2 + 18 * HSTR * 4 + 32 * 48 * 4 + 3 * 4 * 16 * 4)  // 148,224

typedef __attribute__((ext_vector_type(8))) short s16x8;
typedef __attribute__((ext_vector_type(4))) float f32x4;
typedef unsigned long long ull;

__device__ __forceinline__ short f2bf(float x) {
    union { float f; unsigned u; } v; v.f = x;
    unsigned r = (v.u + 0x7fffu + ((v.u >> 16) & 1u)) >> 16;
    return (short)r;
}
__device__ __forceinline__ float bf2f(short b) {
    union { unsigned u; float f; } v; v.u = ((unsigned)(unsigned short)b) << 16;
    return v.f;
}
__device__ __forceinline__ float sigm(float x) { return 1.f / (1.f + __expf(-x)); }
__device__ __forceinline__ float tanh_fast(float x) { return 1.f - 2.f / (1.f + __expf(2.f * x)); }

// ---------------------------------------------------------------------------
// Weight packing (unchanged, proven correct)
// ---------------------------------------------------------------------------
__global__ void k_pack_gru(const float* __restrict__ w_ih,
                           const float* __restrict__ w_hh,
                           short* __restrict__ dst, int KT) {
    int tile = blockIdx.x;
    int ktp  = tile % KT;
    int g    = (tile / KT) % 3;
    int j    = tile / (KT * 3);
    int l    = threadIdx.x;
    int u    = j * 16 + (l & 15);
    int row  = g * H + u;
    const float* src; int k0;
    if (KT == 32) {
        if (ktp < 16) { src = w_ih; k0 = ktp * 32; }
        else          { src = w_hh; k0 = (ktp - 16) * 32; }
    } else          { src = w_hh; k0 = ktp * 32; }
    k0 += (l >> 4) * 8;
    short* p = dst + ((size_t)tile * 64 + l) * 8;
    for (int jj = 0; jj < 8; jj++) {
        int k = k0 + jj;
        float v = 0.f;
        if (u < H && k < H) v = src[(size_t)row * H + k];
        p[jj] = f2bf(v);
    }
}

__global__ void k_pack_fc2(const float* __restrict__ w, short* __restrict__ dst) {
    int tile = blockIdx.x;
    int kt = tile % 16, mt = tile / 16;
    int l = threadIdx.x;
    int o = mt * 16 + (l & 15);
    int k0 = kt * 32 + (l >> 4) * 8;
    short* p = dst + ((size_t)tile * 64 + l) * 8;
    for (int jj = 0; jj < 8; jj++) {
        int k = k0 + jj; float v = 0.f;
        if (o < O_OUT && k < H) v = w[(size_t)o * H + k];
        p[jj] = f2bf(v);
    }
}

__global__ void k_hin(const float* __restrict__ x, const float* __restrict__ w,
                      const float* __restrict__ bias, float* __restrict__ hin) {
    int b = blockIdx.x, o = threadIdx.x;
    float acc = 0.f;
    if (o < D_IN) {
        acc = bias[o];
        for (int k = 0; k < D_IN; k++) acc += x[b * D_IN + k] * w[o * D_IN + k];
        acc = fmaxf(acc, 0.f);
    }
    hin[b * 64 + o] = (o < D_IN) ? acc : 0.f;
}

__global__ void k_g0(const float* __restrict__ hin, const float* __restrict__ w_ih0,
                     const float* __restrict__ b_ih0, float* __restrict__ g0) {
    int b = blockIdx.x, tid = threadIdx.x;
    __shared__ float shx[D_IN];
    if (tid < D_IN) shx[tid] = hin[b * 64 + tid];
    __syncthreads();
    for (int o = tid; o < NP; o += 256) {
        float acc = 0.f;
        if (o < 3 * H) {
            acc = b_ih0[o];
            for (int k = 0; k < D_IN; k++) acc += shx[k] * w_ih0[(size_t)o * D_IN + k];
        }
        g0[(size_t)b * NP + o] = acc;
    }
}

// ---------------------------------------------------------------------------
// One wave role of phase B: NK fully unrolled. Weight stream is software-
// pipelined with a depth-8 rotating register buffer (24 16B loads in flight,
// short live ranges => allocator keeps them in VGPRs). L3 latency of the
// kk+8 weights hides under 8 iterations of ds_read+MFMA.
// ---------------------------------------------------------------------------
template <int NK>
__device__ __forceinline__ void role_mfma(const short* __restrict__ stg, int abase, int ak0,
                                          const short* __restrict__ wg0,
                                          const short* __restrict__ wg1,
                                          const short* __restrict__ wg2,
                                          float* __restrict__ dr, float* __restrict__ dz,
                                          float* __restrict__ dn, int lane) {
    const int arow = lane & 15;
    const int acol = (lane >> 4) * 8;
    constexpr int P = 8;                      // prefetch depth (kt iterations ahead)
    s16x8 wbr[P], wbz[P], wbn[P];
    #pragma unroll
    for (int i = 0; i < P; i++) {
        const int ii = (i < NK) ? i : (NK - 1);   // NK>=8 in practice; guard anyway
        wbr[i] = *(const s16x8*)&wg0[(size_t)ii * 512 + lane * 8];
        wbz[i] = *(const s16x8*)&wg1[(size_t)ii * 512 + lane * 8];
        wbn[i] = *(const s16x8*)&wg2[(size_t)ii * 512 + lane * 8];
    }
    f32x4 ar0 = {0.f,0.f,0.f,0.f}, ar1 = {0.f,0.f,0.f,0.f};
    f32x4 az0 = {0.f,0.f,0.f,0.f}, az1 = {0.f,0.f,0.f,0.f};
    f32x4 an0 = {0.f,0.f,0.f,0.f}, an1 = {0.f,0.f,0.f,0.f};
    #pragma unroll
    for (int kk = 0; kk < NK; kk++) {
        const int sl = kk & (P - 1);          // compile-time after unroll
        s16x8 br = wbr[sl], bz = wbz[sl], bn = wbn[sl];
        if (kk + P < NK) {                    // refill the slot just consumed
            wbr[sl] = *(const s16x8*)&wg0[(size_t)(kk + P) * 512 + lane * 8];
            wbz[sl] = *(const s16x8*)&wg1[(size_t)(kk + P) * 512 + lane * 8];
            wbn[sl] = *(const s16x8*)&wg2[(size_t)(kk + P) * 512 + lane * 8];
        }
        int ak = ak0 + kk;
        s16x8 x0 = *(const s16x8*)&stg[abase + arow * SSTR + ak * 32 + acol];
        s16x8 x1 = *(const s16x8*)&stg[abase + (16 + arow) * SSTR + ak * 32 + acol];
        ar0 = __builtin_amdgcn_mfma_f32_16x16x32_bf16(x0, br, ar0, 0, 0, 0);
        ar1 = __builtin_amdgcn_mfma_f32_16x16x32_bf16(x1, br, ar1, 0, 0, 0);
        az0 = __builtin_amdgcn_mfma_f32_16x16x32_bf16(x0, bz, az0, 0, 0, 0);
        az1 = __builtin_amdgcn_mfma_f32_16x16x32_bf16(x1, bz, az1, 0, 0, 0);
        an0 = __builtin_amdgcn_mfma_f32_16x16x32_bf16(x0, bn, an0, 0, 0, 0);
        an1 = __builtin_amdgcn_mfma_f32_16x16x32_bf16(x1, bn, an1, 0, 0, 0);
    }
    int ul = lane & 15, mrow = (lane >> 4) * 4;
    #pragma unroll
    for (int r = 0; r < 4; r++) {
        dr[(mrow + r) * 18 + ul]      = ar0[r];
        dr[(16 + mrow + r) * 18 + ul] = ar1[r];
        dz[(mrow + r) * 18 + ul]      = az0[r];
        dz[(16 + mrow + r) * 18 + ul] = az1[r];
        dn[(mrow + r) * 18 + ul]      = an0[r];
        dn[(16 + mrow + r) * 18 + ul] = an1[r];
    }
}

// ---------------------------------------------------------------------------
// Persistent pipelined GRU — R13: exact R1 (best, 2252us) structure; the ONLY
// change is role_mfma's depth-8 weight prefetch pipeline. bg = blockIdx&7
// keeps h-exchange XCD-local; weights stream from L3 but latency now hidden.
//   w0: l0 hh k[0:8)   A=SA part0     w1: l0 hh k[8:16) A=SA part1
//   w2: l1 ih          A=SA part0     w3: l1 hh         A=SB part1
//   w4: l2 ih          A=SB part0     w5: l2 hh         A=SC part1
// ---------------------------------------------------------------------------
__global__ __launch_bounds__(384, 2)   // 2 waves/EU min => VGPR cap 256
void k_gru_persist(const short* __restrict__ packW0,
                   const short* __restrict__ packW1,
                   const short* __restrict__ packW2,
                   const float* __restrict__ g0,
                   const float* __restrict__ b_hh0,
                   const float* __restrict__ b_ih1, const float* __restrict__ b_hh1,
                   const float* __restrict__ b_ih2, const float* __restrict__ b_hh2,
                   short* __restrict__ ysA,    // layer0 out at t, overwritten by layer2 at t (step t+2)
                   short* __restrict__ ysB,    // layer1 out
                   unsigned* __restrict__ cnt) {
    const int bg   = blockIdx.x & 7;      // XCD-local batch group (dispatch round-robins XCDs)
    const int j    = blockIdx.x >> 3;     // j-slice 0..31 within the XCD
    const int b0   = bg * 32;
    const int tid  = threadIdx.x;
    const int lane = tid & 63;
    const int wave = tid >> 6;
    const s16x8 z8 = {0, 0, 0, 0, 0, 0, 0, 0};

    extern __shared__ __align__(16) char smem[];
    short* stg = (short*)smem;                         // SA/SB/SC
    float* hgl = (float*)(smem + LDS_STAGE * 2);       // [18][HSTR]
    float* sg0 = hgl + 18 * HSTR;                      // [32*48]
    float* sbb = sg0 + 32 * 48;                        // [3][4][16]

    // ---- wave role parameters (uniform per wave; loop-invariant)
    int abase, ak0, slot0;
    const short* wg0; const short* wg1; const short* wg2;
    {
        const short* wpk; int KT, kt0;
        switch (wave) {
            case 0:  wpk = packW0; KT = 16; kt0 = 0;  abase = LDS_SA; ak0 = 0; slot0 = 0;  break;
            case 1:  wpk = packW0; KT = 16; kt0 = 8;  abase = LDS_SA; ak0 = 8; slot0 = 1;  break;
            case 2:  wpk = packW1; KT = 32; kt0 = 0;  abase = LDS_SA; ak0 = 0; slot0 = 6;  break;
            case 3:  wpk = packW1; KT = 32; kt0 = 16; abase = LDS_SB; ak0 = 0; slot0 = 7;  break;
            case 4:  wpk = packW2; KT = 32; kt0 = 0;  abase = LDS_SB; ak0 = 0; slot0 = 12; break;
            default: wpk = packW2; KT = 32; kt0 = 16; abase = LDS_SC; ak0 = 0; slot0 = 13; break;
        }
        wg0 = wpk + ((size_t)((j * 3 + 0) * KT + kt0) * 512);
        wg1 = wpk + ((size_t)((j * 3 + 1) * KT + kt0) * 512);
        wg2 = wpk + ((size_t)((j * 3 + 2) * KT + kt0) * 512);
    }
    float* dr = hgl + (size_t)slot0 * HSTR;
    float* dz = hgl + (size_t)(slot0 + 2) * HSTR;
    float* dn = hgl + (size_t)(slot0 + 4) * HSTR;

    // ---- layer0 x-gate constants (g0 + b_hh0 folded for r,z)
    for (int c = tid; c < 32 * 48; c += 384) {
        int m = c / 48, col = c % 48;
        int g = col >> 4, ul = col & 15;
        int u = j * 16 + ul;
        float v = 0.f;
        if (u < H) {
            v = g0[(size_t)(b0 + m) * NP + g * H + u];
            if (g == 0) v += b_hh0[u];
            else if (g == 1) v += b_hh0[H + u];
        }
        sg0[m * 48 + col] = v;
    }
    if (tid < 48) {
        int l = tid >> 4, ul = tid & 15, u = j * 16 + ul;
        float br = 0.f, bz = 0.f, bxn = 0.f, bhn = 0.f;
        if (u < H) {
            if (l == 0) bhn = b_hh0[2 * H + u];
            else {
                const float* bi = (l == 1) ? b_ih1 : b_ih2;
                const float* bh = (l == 1) ? b_hh1 : b_hh2;
                br = bi[u] + bh[u]; bz = bi[H + u] + bh[H + u];
                bxn = bi[2 * H + u]; bhn = bh[2 * H + u];
            }
        }
        sbb[(l * 4 + 0) * 16 + ul] = br;  sbb[(l * 4 + 1) * 16 + ul] = bz;
        sbb[(l * 4 + 2) * 16 + ul] = bxn; sbb[(l * 4 + 3) * 16 + ul] = bhn;
    }
    __syncthreads();

    unsigned* mycnt = cnt + bg * 32;   // 128B-strided counters

    for (int s = 0; s < T_STEPS + 2; ++s) {
        const bool hasL0 = (s < T_STEPS);
        const bool hasL1 = (s >= 1 && s <= T_STEPS);
        const bool hasL2 = (s >= 2);
        const short* ysAm1 = ysA + (size_t)(s - 1) * BATCH * HP;
        const short* ysBm2 = ysB + (size_t)(s - 2) * BATCH * HP;
        const short* ysAm3 = ysA + (size_t)(s - 3) * BATCH * HP;

        // ================= PHASE A: coalesced staging of all three tiles ====
        #pragma unroll
        for (int i = 0; i < 6; i++) {
            int c = tid + i * 384;
            if (c < 2048) {
                int r = c >> 6, cc = c & 63;
                size_t goff = (size_t)(b0 + r) * HP + cc * 8;
                s16x8 va = z8, vb = z8, vc = z8;
                if (s >= 1 && s <= T_STEPS) va = *(const s16x8*)&ysAm1[goff];
                if (s >= 2)                 vb = *(const s16x8*)&ysBm2[goff];
                if (s >= 3) {
                    const ull* p = (const ull*)&ysAm3[goff];
                    union { ull q[2]; s16x8 v; } uu;
                    uu.q[0] = __hip_atomic_load(p,     __ATOMIC_RELAXED, __HIP_MEMORY_SCOPE_AGENT);
                    uu.q[1] = __hip_atomic_load(p + 1, __ATOMIC_RELAXED, __HIP_MEMORY_SCOPE_AGENT);
                    vc = uu.v;
                }
                int loff = r * SSTR + cc * 8;
                *(s16x8*)&stg[LDS_SA + loff] = va;
                *(s16x8*)&stg[LDS_SB + loff] = vb;
                *(s16x8*)&stg[LDS_SC + loff] = vc;
            }
        }
        __syncthreads();                                   // (1) tiles staged

        // ================= PHASE B: 6 roles, pipelined weight stream ========
        {
            const bool active = (wave < 2) ? hasL0 : ((wave < 4) ? hasL1 : hasL2);
            if (active) {
                if (wave < 2) role_mfma<8>(stg, abase, ak0, wg0, wg1, wg2, dr, dz, dn, lane);
                else          role_mfma<16>(stg, abase, ak0, wg0, wg1, wg2, dr, dz, dn, lane);
            }
        }
        __syncthreads();                                   // (2) hgl complete

        // ================= PHASE C: all gates (768 items / 384 threads) =====
        #pragma unroll
        for (int it = 0; it < 2; it++) {
            int idx = tid + it * 384;
            int which = idx >> 8, id8 = idx & 255;
            int m = id8 >> 3, pr = id8 & 7;
            int b = b0 + m;
            if (which == 0 && hasL0) {
                short* dst = ysA + (size_t)s * BATCH * HP;
                unsigned pk = 0;
                #pragma unroll
                for (int e = 0; e < 2; e++) {
                    int ul = pr * 2 + e, u = j * 16 + ul, mo = m * 18 + ul;
                    float hv = 0.f;
                    if (u < H) {
                        float hr = hgl[0 * HSTR + mo] + hgl[1 * HSTR + mo];
                        float hz = hgl[2 * HSTR + mo] + hgl[3 * HSTR + mo];
                        float hn = hgl[4 * HSTR + mo] + hgl[5 * HSTR + mo];
                        float r = sigm(sg0[m * 48 + ul] + hr);
                        float z = sigm(sg0[m * 48 + 16 + ul] + hz);
                        float n = tanh_fast(sg0[m * 48 + 32 + ul] + r * (hn + sbb[3 * 16 + ul]));
                        float hold = bf2f(stg[LDS_SA + m * SSTR + u]);
                        hv = (1.f - z) * n + z * hold;
                    }
                    pk |= ((unsigned)(unsigned short)f2bf(hv)) << (16 * e);
                }
                __hip_atomic_store((unsigned*)&dst[(size_t)b * HP + j * 16 + pr * 2], pk,
                                   __ATOMIC_RELAXED, __HIP_MEMORY_SCOPE_AGENT);
            } else if (which == 1 && hasL1) {
                short* dst = ysB + (size_t)(s - 1) * BATCH * HP;
                unsigned pk = 0;
                #pragma unroll
                for (int e = 0; e < 2; e++) {
                    int ul = pr * 2 + e, u = j * 16 + ul, mo = m * 18 + ul;
                    float hv = 0.f;
                    if (u < H) {
                        float xr = hgl[6 * HSTR + mo]  + sbb[(4 + 0) * 16 + ul];
                        float hr = hgl[7 * HSTR + mo];
                        float xz = hgl[8 * HSTR + mo]  + sbb[(4 + 1) * 16 + ul];
                        float hz = hgl[9 * HSTR + mo];
                        float xn = hgl[10 * HSTR + mo] + sbb[(4 + 2) * 16 + ul];
                        float hn = hgl[11 * HSTR + mo] + sbb[(4 + 3) * 16 + ul];
                        float r = sigm(xr + hr);
                        float z = sigm(xz + hz);
                        float n = tanh_fast(xn + r * hn);
                        float hold = bf2f(stg[LDS_SB + m * SSTR + u]);
                        hv = (1.f - z) * n + z * hold;
                    }
                    pk |= ((unsigned)(unsigned short)f2bf(hv)) << (16 * e);
                }
                __hip_atomic_store((unsigned*)&dst[(size_t)b * HP + j * 16 + pr * 2], pk,
                                   __ATOMIC_RELAXED, __HIP_MEMORY_SCOPE_AGENT);
            } else if (which == 2 && hasL2) {
                short* dst = ysA + (size_t)(s - 2) * BATCH * HP;
                unsigned pk = 0;
                #pragma unroll
                for (int e = 0; e < 2; e++) {
                    int ul = pr * 2 + e, u = j * 16 + ul, mo = m * 18 + ul;
                    float hv = 0.f;
                    if (u < H) {
                        float xr = hgl[12 * HSTR + mo] + sbb[(8 + 0) * 16 + ul];
                        float hr = hgl[13 * HSTR + mo];
                        float xz = hgl[14 * HSTR + mo] + sbb[(8 + 1) * 16 + ul];
                        float hz = hgl[15 * HSTR + mo];
                        float xn = hgl[16 * HSTR + mo] + sbb[(8 + 2) * 16 + ul];
                        float hn = hgl[17 * HSTR + mo] + sbb[(8 + 3) * 16 + ul];
                        float r = sigm(xr + hr);
                        float z = sigm(xz + hz);
                        float n = tanh_fast(xn + r * hn);
                        float hold = bf2f(stg[LDS_SC + m * SSTR + u]);
                        hv = (1.f - z) * n + z * hold;
                    }
                    pk |= ((unsigned)(unsigned short)f2bf(hv)) << (16 * e);
                }
                __hip_atomic_store((unsigned*)&dst[(size_t)b * HP + j * 16 + pr * 2], pk,
                                   __ATOMIC_RELAXED, __HIP_MEMORY_SCOPE_AGENT);
            }
        }
        __syncthreads();    // (3) every wave's stores drained at barrier

        // ---- per-bg 32-block barrier: relaxed add + relaxed poll
        if (tid == 0) {
            asm volatile("s_waitcnt vmcnt(0)" ::: "memory");
            __hip_atomic_fetch_add(mycnt, 1u, __ATOMIC_RELAXED, __HIP_MEMORY_SCOPE_AGENT);
            unsigned tgt = 32u * (unsigned)(s + 1);
            while (__hip_atomic_load(mycnt, __ATOMIC_RELAXED, __HIP_MEMORY_SCOPE_AGENT) < tgt) {}
        }
        __syncthreads();                                   // (4)
    }
}

// ---------------------------------------------------------------------------
// fc2 + transpose (reads ysA = layer2 output; fresh kernel => coherent)
// ---------------------------------------------------------------------------
__global__ __launch_bounds__(256, 1)
void k_fc2(const short* __restrict__ ys2, const short* __restrict__ fc2p,
           const float* __restrict__ fc2_b, float* __restrict__ out) {
    int b = blockIdx.x;
    int tid = threadIdx.x, lane = tid & 63, wave = tid >> 6;
    const s16x8 zf = {0, 0, 0, 0, 0, 0, 0, 0};
    for (int ntile = wave; ntile < 18; ntile += 4) {
        int tt = ntile * 16 + (lane & 15);
        s16x8 bf[16];
        for (int kt = 0; kt < 16; kt++) {
            if (tt < T_STEPS)
                bf[kt] = *(const s16x8*)&ys2[((size_t)tt * BATCH + b) * HP + kt * 32 + (lane >> 4) * 8];
            else
                bf[kt] = zf;
        }
        for (int mt = 0; mt < 5; mt++) {
            f32x4 acc = {0.f, 0.f, 0.f, 0.f};
            for (int kt = 0; kt < 16; kt++) {
                s16x8 af = *(const s16x8*)&fc2p[(((size_t)mt * 16 + kt) * 64 + lane) * 8];
                acc = __builtin_amdgcn_mfma_f32_16x16x32_bf16(af, bf[kt], acc, 0, 0, 0);
            }
            int obase = mt * 16 + (lane >> 4) * 4;
            for (int r = 0; r < 4; r++) {
                int o = obase + r;
                if (o < O_OUT && tt < T_STEPS)
                    out[((size_t)b * O_OUT + o) * T_STEPS + tt] = acc[r] + fc2_b[o];
            }
        }
    }
}

// ---------------------------------------------------------------------------
extern "C" void kernel_launch(void* const* d_in, const int* in_sizes, int n_in,
                              void* d_out, int out_size, void* d_ws, size_t ws_size,
                              hipStream_t stream) {
    const float* x     = (const float*)d_in[0];
    const float* fc1_w = (const float*)d_in[1];
    const float* fc1_b = (const float*)d_in[2];
    const float* w_ih0 = (const float*)d_in[3];
    const float* w_hh0 = (const float*)d_in[4];
    const float* b_ih0 = (const float*)d_in[5];
    const float* b_hh0 = (const float*)d_in[6];
    const float* w_ih1 = (const float*)d_in[7];
    const float* w_hh1 = (const float*)d_in[8];
    const float* b_ih1 = (const float*)d_in[9];
    const float* b_hh1 = (const float*)d_in[10];
    const float* w_ih2 = (const float*)d_in[11];
    const float* w_hh2 = (const float*)d_in[12];
    const float* b_ih2 = (const float*)d_in[13];
    const float* b_hh2 = (const float*)d_in[14];
    const float* fc2_w = (const float*)d_in[15];
    const float* fc2_b = (const float*)d_in[16];
    float* out = (float*)d_out;

    char* p = (char*)d_ws;
    auto alloc = [&](size_t bytes) {
        char* r = p; p += (bytes + 255) & ~(size_t)255; return r;
    };
    short* packW0 = (short*)alloc((size_t)32 * 3 * 16 * 64 * 8 * 2);
    short* packW1 = (short*)alloc((size_t)32 * 3 * 32 * 64 * 8 * 2);
    short* packW2 = (short*)alloc((size_t)32 * 3 * 32 * 64 * 8 * 2);
    short* packF  = (short*)alloc((size_t)80 * 64 * 8 * 2);
    float* hin    = (float*)alloc((size_t)BATCH * 64 * 4);
    float* g0     = (float*)alloc((size_t)BATCH * NP * 4);
    unsigned* cnt = (unsigned*)alloc(256 * 4);
    short* ysA    = (short*)alloc((size_t)T_STEPS * BATCH * HP * 2);
    short* ysB    = (short*)alloc((size_t)T_STEPS * BATCH * HP * 2);

    // opt in to >64KB dynamic LDS (host-side attribute; graph-capture safe)
    static bool attr_set = false;
    if (!attr_set) {
        (void)hipFuncSetAttribute((const void*)k_gru_persist,
                                  hipFuncAttributeMaxDynamicSharedMemorySize,
                                  DYN_LDS);
        attr_set = true;
    }

    hipMemsetAsync(cnt, 0, 256 * 4, stream);
    k_pack_gru<<<32 * 3 * 16, 64, 0, stream>>>(nullptr, w_hh0, packW0, 16);
    k_pack_gru<<<32 * 3 * 32, 64, 0, stream>>>(w_ih1, w_hh1, packW1, 32);
    k_pack_gru<<<32 * 3 * 32, 64, 0, stream>>>(w_ih2, w_hh2, packW2, 32);
    k_pack_fc2<<<80, 64, 0, stream>>>(fc2_w, packF);
    k_hin<<<BATCH, 64, 0, stream>>>(x, fc1_w, fc1_b, hin);
    k_g0<<<BATCH, 256, 0, stream>>>(hin, w_ih0, b_ih0, g0);

    k_gru_persist<<<256, 384, DYN_LDS, stream>>>(packW0, packW1, packW2, g0,
                                                 b_hh0, b_ih1, b_hh1, b_ih2, b_hh2,
                                                 ysA, ysB, cnt);

    k_fc2<<<BATCH, 256, 0, stream>>>(ysA, packF, fc2_b, out);
}

// Round 5
// 4154.609 us; speedup vs baseline: 1.9981x; 1.4112x over previous
//
#include <hip/hip_runtime.h>
#include <hip/hip_bf16.h>
#include <math.h>

#define D_IN 56
#define H    501
#define T_STEPS 277
#define O_OUT 76
#define BATCH 256
#define HP   512    // padded K (hidden) for MFMA
#define NP   1504   // padded 3H
#define SSTR 520    // LDS staging row stride in shorts (1040B, 16B-aligned)
#define HSTR 576    // hgl slot size in floats (32 rows * 18)
#define NSLOT 20    // 5 groups x [r, z0, z1, n]

// dynamic LDS layout: SA | SB | SC | hgl[20][576] | sg0[32*48] | sb[3*4*16]
#define LDS_SA    0
#define LDS_SB    (32 * SSTR)
#define LDS_SC    (64 * SSTR)
#define LDS_STAGE (96 * SSTR)                 // 99,840 B staging (shorts)
#define DYN_LDS   (96 * SSTR * 2 + NSLOT * HSTR * 4 + 32 * 48 * 4 + 3 * 4 * 16 * 4)  // 152,832

typedef __attribute__((ext_vector_type(8))) short s16x8;
typedef __attribute__((ext_vector_type(4))) float f32x4;
typedef unsigned long long ull;

__device__ __forceinline__ short f2bf(float x) {
    union { float f; unsigned u; } v; v.f = x;
    unsigned r = (v.u + 0x7fffu + ((v.u >> 16) & 1u)) >> 16;
    return (short)r;
}
__device__ __forceinline__ float bf2f(short b) {
    union { unsigned u; float f; } v; v.u = ((unsigned)(unsigned short)b) << 16;
    return v.f;
}
__device__ __forceinline__ float sigm(float x) { return 1.f / (1.f + __expf(-x)); }
__device__ __forceinline__ float tanh_fast(float x) { return 1.f - 2.f / (1.f + __expf(2.f * x)); }

// ---------------------------------------------------------------------------
// Weight packing (unchanged, proven correct)
// ---------------------------------------------------------------------------
__global__ void k_pack_gru(const float* __restrict__ w_ih,
                           const float* __restrict__ w_hh,
                           short* __restrict__ dst, int KT) {
    int tile = blockIdx.x;
    int ktp  = tile % KT;
    int g    = (tile / KT) % 3;
    int j    = tile / (KT * 3);
    int l    = threadIdx.x;
    int u    = j * 16 + (l & 15);
    int row  = g * H + u;
    const float* src; int k0;
    if (KT == 32) {
        if (ktp < 16) { src = w_ih; k0 = ktp * 32; }
        else          { src = w_hh; k0 = (ktp - 16) * 32; }
    } else          { src = w_hh; k0 = ktp * 32; }
    k0 += (l >> 4) * 8;
    short* p = dst + ((size_t)tile * 64 + l) * 8;
    for (int jj = 0; jj < 8; jj++) {
        int k = k0 + jj;
        float v = 0.f;
        if (u < H && k < H) v = src[(size_t)row * H + k];
        p[jj] = f2bf(v);
    }
}

__global__ void k_pack_fc2(const float* __restrict__ w, short* __restrict__ dst) {
    int tile = blockIdx.x;
    int kt = tile % 16, mt = tile / 16;
    int l = threadIdx.x;
    int o = mt * 16 + (l & 15);
    int k0 = kt * 32 + (l >> 4) * 8;
    short* p = dst + ((size_t)tile * 64 + l) * 8;
    for (int jj = 0; jj < 8; jj++) {
        int k = k0 + jj; float v = 0.f;
        if (o < O_OUT && k < H) v = w[(size_t)o * H + k];
        p[jj] = f2bf(v);
    }
}

__global__ void k_hin(const float* __restrict__ x, const float* __restrict__ w,
                      const float* __restrict__ bias, float* __restrict__ hin) {
    int b = blockIdx.x, o = threadIdx.x;
    float acc = 0.f;
    if (o < D_IN) {
        acc = bias[o];
        for (int k = 0; k < D_IN; k++) acc += x[b * D_IN + k] * w[o * D_IN + k];
        acc = fmaxf(acc, 0.f);
    }
    hin[b * 64 + o] = (o < D_IN) ? acc : 0.f;
}

__global__ void k_g0(const float* __restrict__ hin, const float* __restrict__ w_ih0,
                     const float* __restrict__ b_ih0, float* __restrict__ g0) {
    int b = blockIdx.x, tid = threadIdx.x;
    __shared__ float shx[D_IN];
    if (tid < D_IN) shx[tid] = hin[b * 64 + tid];
    __syncthreads();
    for (int o = tid; o < NP; o += 256) {
        float acc = 0.f;
        if (o < 3 * H) {
            acc = b_ih0[o];
            for (int k = 0; k < D_IN; k++) acc += shx[k] * w_ih0[(size_t)o * D_IN + k];
        }
        g0[(size_t)b * NP + o] = acc;
    }
}

// ---------------------------------------------------------------------------
// One wave's phase-B role: TWO gate-segments merged in one unrolled loop so
// their weight loads interleave (compiler-scheduled, no manual buffers —
// R3/R4 proved hand-managed weight registers always lose). 24 loads/wave.
// Results are complete sums written to private hgl slots (no atomics).
// ---------------------------------------------------------------------------
template <int NKA, int NKB>
__device__ __forceinline__ void role2(const short* __restrict__ stg, int abase,
                                      const short* __restrict__ wA, int akA0,
                                      const short* __restrict__ wB, int akB0,
                                      float* __restrict__ dA, float* __restrict__ dB,
                                      int lane) {
    const int arow = lane & 15;
    const int acol = (lane >> 4) * 8;
    f32x4 aA0 = {0.f,0.f,0.f,0.f}, aA1 = {0.f,0.f,0.f,0.f};
    f32x4 aB0 = {0.f,0.f,0.f,0.f}, aB1 = {0.f,0.f,0.f,0.f};
    constexpr int NKM = (NKA > NKB) ? NKA : NKB;
    #pragma unroll
    for (int kk = 0; kk < NKM; kk++) {
        if (kk < NKA) {
            s16x8 w = *(const s16x8*)&wA[(size_t)kk * 512 + lane * 8];
            int ak = akA0 + kk;
            s16x8 x0 = *(const s16x8*)&stg[abase + arow * SSTR + ak * 32 + acol];
            s16x8 x1 = *(const s16x8*)&stg[abase + (16 + arow) * SSTR + ak * 32 + acol];
            aA0 = __builtin_amdgcn_mfma_f32_16x16x32_bf16(x0, w, aA0, 0, 0, 0);
            aA1 = __builtin_amdgcn_mfma_f32_16x16x32_bf16(x1, w, aA1, 0, 0, 0);
        }
        if (kk < NKB) {
            s16x8 w = *(const s16x8*)&wB[(size_t)kk * 512 + lane * 8];
            int ak = akB0 + kk;
            s16x8 x0 = *(const s16x8*)&stg[abase + arow * SSTR + ak * 32 + acol];
            s16x8 x1 = *(const s16x8*)&stg[abase + (16 + arow) * SSTR + ak * 32 + acol];
            aB0 = __builtin_amdgcn_mfma_f32_16x16x32_bf16(x0, w, aB0, 0, 0, 0);
            aB1 = __builtin_amdgcn_mfma_f32_16x16x32_bf16(x1, w, aB1, 0, 0, 0);
        }
    }
    const int ul = lane & 15, mrow = (lane >> 4) * 4;
    #pragma unroll
    for (int r = 0; r < 4; r++) {
        dA[(mrow + r) * 18 + ul]      = aA0[r];
        dA[(16 + mrow + r) * 18 + ul] = aA1[r];
        dB[(mrow + r) * 18 + ul]      = aB0[r];
        dB[(16 + mrow + r) * 18 + ul] = aB1[r];
    }
}

// ---------------------------------------------------------------------------
// Persistent pipelined GRU — R14: R1 (best, 2252us) structure with phase B
// re-decomposed into 10 uniform wave roles (640 threads, 2.5 waves/SIMD):
// each wave = 24 weight loads + 48 MFMAs (vs R1 heavy waves' 48+96), halving
// the per-wave exposed L3 latency chain and adding cross-wave overlap.
// Groups g0..g4 = L0hh(SA) L1ih(SA) L1hh(SB) L2ih(SB) L2hh(SC); wave pair
// (2g, 2g+1): sub0 = gate r kt0-15 + gate z kt0-7; sub1 = gate z kt8-15 +
// gate n kt0-15. hgl = 20 slots [r, z0, z1, n] per group; no atomics.
// ---------------------------------------------------------------------------
__global__ __launch_bounds__(640, 2)
void k_gru_persist(const short* __restrict__ packW0,
                   const short* __restrict__ packW1,
                   const short* __restrict__ packW2,
                   const float* __restrict__ g0,
                   const float* __restrict__ b_hh0,
                   const float* __restrict__ b_ih1, const float* __restrict__ b_hh1,
                   const float* __restrict__ b_ih2, const float* __restrict__ b_hh2,
                   short* __restrict__ ysA,    // layer0 out at t, overwritten by layer2 at t (step t+2)
                   short* __restrict__ ysB,    // layer1 out
                   unsigned* __restrict__ cnt) {
    const int bg   = blockIdx.x & 7;      // XCD-local batch group (dispatch round-robins XCDs)
    const int j    = blockIdx.x >> 3;     // j-slice 0..31 within the XCD
    const int b0   = bg * 32;
    const int tid  = threadIdx.x;
    const int lane = tid & 63;
    const int wave = tid >> 6;            // 0..9
    const s16x8 z8 = {0, 0, 0, 0, 0, 0, 0, 0};

    extern __shared__ __align__(16) char smem[];
    short* stg = (short*)smem;                         // SA/SB/SC
    float* hgl = (float*)(smem + LDS_STAGE * 2);       // [NSLOT][HSTR]
    float* sg0 = hgl + NSLOT * HSTR;                   // [32*48]
    float* sbb = sg0 + 32 * 48;                        // [3][4][16]

    // ---- wave role parameters (uniform per wave; loop-invariant)
    const int grp = wave >> 1;            // 0..4
    const int sub = wave & 1;
    int abase;
    const short* wpk; int KT, kt0;
    switch (grp) {
        case 0:  wpk = packW0; KT = 16; kt0 = 0;  abase = LDS_SA; break;
        case 1:  wpk = packW1; KT = 32; kt0 = 0;  abase = LDS_SA; break;
        case 2:  wpk = packW1; KT = 32; kt0 = 16; abase = LDS_SB; break;
        case 3:  wpk = packW2; KT = 32; kt0 = 0;  abase = LDS_SB; break;
        default: wpk = packW2; KT = 32; kt0 = 16; abase = LDS_SC; break;
    }
    const short* wr = wpk + ((size_t)((j * 3 + 0) * KT + kt0) * 512);
    const short* wz = wpk + ((size_t)((j * 3 + 1) * KT + kt0) * 512);
    const short* wn = wpk + ((size_t)((j * 3 + 2) * KT + kt0) * 512);
    float* slotb = hgl + (size_t)(4 * grp) * HSTR;     // [r, z0, z1, n]

    // ---- layer0 x-gate constants (g0 + b_hh0 folded for r,z)
    for (int c = tid; c < 32 * 48; c += 640) {
        int m = c / 48, col = c % 48;
        int g = col >> 4, ul = col & 15;
        int u = j * 16 + ul;
        float v = 0.f;
        if (u < H) {
            v = g0[(size_t)(b0 + m) * NP + g * H + u];
            if (g == 0) v += b_hh0[u];
            else if (g == 1) v += b_hh0[H + u];
        }
        sg0[m * 48 + col] = v;
    }
    if (tid < 48) {
        int l = tid >> 4, ul = tid & 15, u = j * 16 + ul;
        float br = 0.f, bz = 0.f, bxn = 0.f, bhn = 0.f;
        if (u < H) {
            if (l == 0) bhn = b_hh0[2 * H + u];
            else {
                const float* bi = (l == 1) ? b_ih1 : b_ih2;
                const float* bh = (l == 1) ? b_hh1 : b_hh2;
                br = bi[u] + bh[u]; bz = bi[H + u] + bh[H + u];
                bxn = bi[2 * H + u]; bhn = bh[2 * H + u];
            }
        }
        sbb[(l * 4 + 0) * 16 + ul] = br;  sbb[(l * 4 + 1) * 16 + ul] = bz;
        sbb[(l * 4 + 2) * 16 + ul] = bxn; sbb[(l * 4 + 3) * 16 + ul] = bhn;
    }
    __syncthreads();

    unsigned* mycnt = cnt + bg * 32;   // 128B-strided counters

    for (int s = 0; s < T_STEPS + 2; ++s) {
        const bool hasL0 = (s < T_STEPS);
        const bool hasL1 = (s >= 1 && s <= T_STEPS);
        const bool hasL2 = (s >= 2);
        const short* ysAm1 = ysA + (size_t)(s - 1) * BATCH * HP;
        const short* ysBm2 = ysB + (size_t)(s - 2) * BATCH * HP;
        const short* ysAm3 = ysA + (size_t)(s - 3) * BATCH * HP;

        // ================= PHASE A: coalesced staging of all three tiles ====
        for (int c = tid; c < 2048; c += 640) {
            int r = c >> 6, cc = c & 63;
            size_t goff = (size_t)(b0 + r) * HP + cc * 8;
            s16x8 va = z8, vb = z8, vc = z8;
            if (s >= 1 && s <= T_STEPS) va = *(const s16x8*)&ysAm1[goff];
            if (s >= 2)                 vb = *(const s16x8*)&ysBm2[goff];
            if (s >= 3) {
                const ull* p = (const ull*)&ysAm3[goff];
                union { ull q[2]; s16x8 v; } uu;
                uu.q[0] = __hip_atomic_load(p,     __ATOMIC_RELAXED, __HIP_MEMORY_SCOPE_AGENT);
                uu.q[1] = __hip_atomic_load(p + 1, __ATOMIC_RELAXED, __HIP_MEMORY_SCOPE_AGENT);
                vc = uu.v;
            }
            int loff = r * SSTR + cc * 8;
            *(s16x8*)&stg[LDS_SA + loff] = va;
            *(s16x8*)&stg[LDS_SB + loff] = vb;
            *(s16x8*)&stg[LDS_SC + loff] = vc;
        }
        __syncthreads();                                   // (1) tiles staged

        // ================= PHASE B: 10 uniform roles, 24 loads each =========
        {
            const bool active = (grp == 0) ? hasL0 : ((grp < 3) ? hasL1 : hasL2);
            if (active) {
                if (sub == 0)
                    role2<16, 8>(stg, abase, wr, 0, wz, 0,
                                 slotb + 0 * HSTR, slotb + 1 * HSTR, lane);
                else
                    role2<8, 16>(stg, abase, wz + (size_t)8 * 512, 8, wn, 0,
                                 slotb + 2 * HSTR, slotb + 3 * HSTR, lane);
            }
        }
        __syncthreads();                                   // (2) hgl complete

        // ================= PHASE C: all gates (768 items / 640 threads) =====
        for (int idx = tid; idx < 768; idx += 640) {
            int which = idx >> 8, id8 = idx & 255;
            int m = id8 >> 3, pr = id8 & 7;
            int b = b0 + m;
            if (which == 0 && hasL0) {
                short* dst = ysA + (size_t)s * BATCH * HP;
                unsigned pk = 0;
                #pragma unroll
                for (int e = 0; e < 2; e++) {
                    int ul = pr * 2 + e, u = j * 16 + ul, mo = m * 18 + ul;
                    float hv = 0.f;
                    if (u < H) {
                        float hr = hgl[0 * HSTR + mo];
                        float hz = hgl[1 * HSTR + mo] + hgl[2 * HSTR + mo];
                        float hn = hgl[3 * HSTR + mo];
                        float r = sigm(sg0[m * 48 + ul] + hr);
                        float z = sigm(sg0[m * 48 + 16 + ul] + hz);
                        float n = tanh_fast(sg0[m * 48 + 32 + ul] + r * (hn + sbb[3 * 16 + ul]));
                        float hold = bf2f(stg[LDS_SA + m * SSTR + u]);
                        hv = (1.f - z) * n + z * hold;
                    }
                    pk |= ((unsigned)(unsigned short)f2bf(hv)) << (16 * e);
                }
                __hip_atomic_store((unsigned*)&dst[(size_t)b * HP + j * 16 + pr * 2], pk,
                                   __ATOMIC_RELAXED, __HIP_MEMORY_SCOPE_AGENT);
            } else if (which == 1 && hasL1) {
                short* dst = ysB + (size_t)(s - 1) * BATCH * HP;
                unsigned pk = 0;
                #pragma unroll
                for (int e = 0; e < 2; e++) {
                    int ul = pr * 2 + e, u = j * 16 + ul, mo = m * 18 + ul;
                    float hv = 0.f;
                    if (u < H) {
                        float xr = hgl[4 * HSTR + mo] + sbb[(4 + 0) * 16 + ul];
                        float xz = hgl[5 * HSTR + mo] + hgl[6 * HSTR + mo] + sbb[(4 + 1) * 16 + ul];
                        float xn = hgl[7 * HSTR + mo] + sbb[(4 + 2) * 16 + ul];
                        float hr = hgl[8 * HSTR + mo];
                        float hz = hgl[9 * HSTR + mo] + hgl[10 * HSTR + mo];
                        float hn = hgl[11 * HSTR + mo] + sbb[(4 + 3) * 16 + ul];
                        float r = sigm(xr + hr);
                        float z = sigm(xz + hz);
                        float n = tanh_fast(xn + r * hn);
                        float hold = bf2f(stg[LDS_SB + m * SSTR + u]);
                        hv = (1.f - z) * n + z * hold;
                    }
                    pk |= ((unsigned)(unsigned short)f2bf(hv)) << (16 * e);
                }
                __hip_atomic_store((unsigned*)&dst[(size_t)b * HP + j * 16 + pr * 2], pk,
                                   __ATOMIC_RELAXED, __HIP_MEMORY_SCOPE_AGENT);
            } else if (which == 2 && hasL2) {
                short* dst = ysA + (size_t)(s - 2) * BATCH * HP;
                unsigned pk = 0;
                #pragma unroll
                for (int e = 0; e < 2; e++) {
                    int ul = pr * 2 + e, u = j * 16 + ul, mo = m * 18 + ul;
                    float hv = 0.f;
                    if (u < H) {
                        float xr = hgl[12 * HSTR + mo] + sbb[(8 + 0) * 16 + ul];
                        float xz = hgl[13 * HSTR + mo] + hgl[14 * HSTR + mo] + sbb[(8 + 1) * 16 + ul];
                        float xn = hgl[15 * HSTR + mo] + sbb[(8 + 2) * 16 + ul];
                        float hr = hgl[16 * HSTR + mo];
                        float hz = hgl[17 * HSTR + mo] + hgl[18 * HSTR + mo];
                        float hn = hgl[19 * HSTR + mo] + sbb[(8 + 3) * 16 + ul];
                        float r = sigm(xr + hr);
                        float z = sigm(xz + hz);
                        float n = tanh_fast(xn + r * hn);
                        float hold = bf2f(stg[LDS_SC + m * SSTR + u]);
                        hv = (1.f - z) * n + z * hold;
                    }
                    pk |= ((unsigned)(unsigned short)f2bf(hv)) << (16 * e);
                }
                __hip_atomic_store((unsigned*)&dst[(size_t)b * HP + j * 16 + pr * 2], pk,
                                   __ATOMIC_RELAXED, __HIP_MEMORY_SCOPE_AGENT);
            }
        }
        __syncthreads();    // (3) every wave's stores drained at barrier

        // ---- per-bg 32-block barrier: relaxed add + relaxed poll
        if (tid == 0) {
            asm volatile("s_waitcnt vmcnt(0)" ::: "memory");
            __hip_atomic_fetch_add(mycnt, 1u, __ATOMIC_RELAXED, __HIP_MEMORY_SCOPE_AGENT);
            unsigned tgt = 32u * (unsigned)(s + 1);
            while (__hip_atomic_load(mycnt, __ATOMIC_RELAXED, __HIP_MEMORY_SCOPE_AGENT) < tgt) {}
        }
        __syncthreads();                                   // (4)
    }
}

// ---------------------------------------------------------------------------
// fc2 + transpose (reads ysA = layer2 output; fresh kernel => coherent)
// ---------------------------------------------------------------------------
__global__ __launch_bounds__(256, 1)
void k_fc2(const short* __restrict__ ys2, const short* __restrict__ fc2p,
           const float* __restrict__ fc2_b, float* __restrict__ out) {
    int b = blockIdx.x;
    int tid = threadIdx.x, lane = tid & 63, wave = tid >> 6;
    const s16x8 zf = {0, 0, 0, 0, 0, 0, 0, 0};
    for (int ntile = wave; ntile < 18; ntile += 4) {
        int tt = ntile * 16 + (lane & 15);
        s16x8 bf[16];
        for (int kt = 0; kt < 16; kt++) {
            if (tt < T_STEPS)
                bf[kt] = *(const s16x8*)&ys2[((size_t)tt * BATCH + b) * HP + kt * 32 + (lane >> 4) * 8];
            else
                bf[kt] = zf;
        }
        for (int mt = 0; mt < 5; mt++) {
            f32x4 acc = {0.f, 0.f, 0.f, 0.f};
            for (int kt = 0; kt < 16; kt++) {
                s16x8 af = *(const s16x8*)&fc2p[(((size_t)mt * 16 + kt) * 64 + lane) * 8];
                acc = __builtin_amdgcn_mfma_f32_16x16x32_bf16(af, bf[kt], acc, 0, 0, 0);
            }
            int obase = mt * 16 + (lane >> 4) * 4;
            for (int r = 0; r < 4; r++) {
                int o = obase + r;
                if (o < O_OUT && tt < T_STEPS)
                    out[((size_t)b * O_OUT + o) * T_STEPS + tt] = acc[r] + fc2_b[o];
            }
        }
    }
}

// ---------------------------------------------------------------------------
extern "C" void kernel_launch(void* const* d_in, const int* in_sizes, int n_in,
                              void* d_out, int out_size, void* d_ws, size_t ws_size,
                              hipStream_t stream) {
    const float* x     = (const float*)d_in[0];
    const float* fc1_w = (const float*)d_in[1];
    const float* fc1_b = (const float*)d_in[2];
    const float* w_ih0 = (const float*)d_in[3];
    const float* w_hh0 = (const float*)d_in[4];
    const float* b_ih0 = (const float*)d_in[5];
    const float* b_hh0 = (const float*)d_in[6];
    const float* w_ih1 = (const float*)d_in[7];
    const float* w_hh1 = (const float*)d_in[8];
    const float* b_ih1 = (const float*)d_in[9];
    const float* b_hh1 = (const float*)d_in[10];
    const float* w_ih2 = (const float*)d_in[11];
    const float* w_hh2 = (const float*)d_in[12];
    const float* b_ih2 = (const float*)d_in[13];
    const float* b_hh2 = (const float*)d_in[14];
    const float* fc2_w = (const float*)d_in[15];
    const float* fc2_b = (const float*)d_in[16];
    float* out = (float*)d_out;

    char* p = (char*)d_ws;
    auto alloc = [&](size_t bytes) {
        char* r = p; p += (bytes + 255) & ~(size_t)255; return r;
    };
    short* packW0 = (short*)alloc((size_t)32 * 3 * 16 * 64 * 8 * 2);
    short* packW1 = (short*)alloc((size_t)32 * 3 * 32 * 64 * 8 * 2);
    short* packW2 = (short*)alloc((size_t)32 * 3 * 32 * 64 * 8 * 2);
    short* packF  = (short*)alloc((size_t)80 * 64 * 8 * 2);
    float* hin    = (float*)alloc((size_t)BATCH * 64 * 4);
    float* g0     = (float*)alloc((size_t)BATCH * NP * 4);
    unsigned* cnt = (unsigned*)alloc(256 * 4);
    short* ysA    = (short*)alloc((size_t)T_STEPS * BATCH * HP * 2);
    short* ysB    = (short*)alloc((size_t)T_STEPS * BATCH * HP * 2);

    // opt in to >64KB dynamic LDS (host-side attribute; graph-capture safe)
    static bool attr_set = false;
    if (!attr_set) {
        (void)hipFuncSetAttribute((const void*)k_gru_persist,
                                  hipFuncAttributeMaxDynamicSharedMemorySize,
                                  DYN_LDS);
        attr_set = true;
    }

    hipMemsetAsync(cnt, 0, 256 * 4, stream);
    k_pack_gru<<<32 * 3 * 16, 64, 0, stream>>>(nullptr, w_hh0, packW0, 16);
    k_pack_gru<<<32 * 3 * 32, 64, 0, stream>>>(w_ih1, w_hh1, packW1, 32);
    k_pack_gru<<<32 * 3 * 32, 64, 0, stream>>>(w_ih2, w_hh2, packW2, 32);
    k_pack_fc2<<<80, 64, 0, stream>>>(fc2_w, packF);
    k_hin<<<BATCH, 64, 0, stream>>>(x, fc1_w, fc1_b, hin);
    k_g0<<<BATCH, 256, 0, stream>>>(hin, w_ih0, b_ih0, g0);

    k_gru_persist<<<256, 640, DYN_LDS, stream>>>(packW0, packW1, packW2, g0,
                                                 b_hh0, b_ih1, b_hh1, b_ih2, b_hh2,
                                                 ysA, ysB, cnt);

    k_fc2<<<BATCH, 256, 0, stream>>>(ysA, packF, fc2_b, out);
}

// Round 7
// 3845.098 us; speedup vs baseline: 2.1590x; 1.0805x over previous
//
#include <hip/hip_runtime.h>
#include <hip/hip_bf16.h>
#include <math.h>

#define D_IN 56
#define H    501
#define T_STEPS 277
#define O_OUT 76
#define BATCH 256
#define HP   512    // padded K (hidden) for MFMA
#define NP   1504   // padded 3H
#define SSTR 520    // LDS staging row stride in shorts (1040B, 16B-aligned)
#define HSTR 576    // hgl slot size in floats (32 rows * 18)

// dynamic LDS layout: SA | SB | SC | hgl[18][576] | sg0[32*48] | sb[3*4*16]
#define LDS_SA    0
#define LDS_SB    (32 * SSTR)
#define LDS_SC    (64 * SSTR)
#define LDS_STAGE (96 * SSTR)                 // 99,840 B staging (shorts)
#define DYN_LDS   (96 * SSTR * 2 + 18 * HSTR * 4 + 32 * 48 * 4 + 3 * 4 * 16 * 4)  // 148,224

typedef __attribute__((ext_vector_type(8))) short s16x8;
typedef __attribute__((ext_vector_type(4))) float f32x4;
typedef unsigned long long ull;

__device__ __forceinline__ short f2bf(float x) {
    union { float f; unsigned u; } v; v.f = x;
    unsigned r = (v.u + 0x7fffu + ((v.u >> 16) & 1u)) >> 16;
    return (short)r;
}
__device__ __forceinline__ float bf2f(short b) {
    union { unsigned u; float f; } v; v.u = ((unsigned)(unsigned short)b) << 16;
    return v.f;
}
__device__ __forceinline__ float sigm(float x) { return 1.f / (1.f + __expf(-x)); }
__device__ __forceinline__ float tanh_fast(float x) { return 1.f - 2.f / (1.f + __expf(2.f * x)); }

// ---------------------------------------------------------------------------
// Weight packing (unchanged, proven correct)
// ---------------------------------------------------------------------------
__global__ void k_pack_gru(const float* __restrict__ w_ih,
                           const float* __restrict__ w_hh,
                           short* __restrict__ dst, int KT) {
    int tile = blockIdx.x;
    int ktp  = tile % KT;
    int g    = (tile / KT) % 3;
    int j    = tile / (KT * 3);
    int l    = threadIdx.x;
    int u    = j * 16 + (l & 15);
    int row  = g * H + u;
    const float* src; int k0;
    if (KT == 32) {
        if (ktp < 16) { src = w_ih; k0 = ktp * 32; }
        else          { src = w_hh; k0 = (ktp - 16) * 32; }
    } else          { src = w_hh; k0 = ktp * 32; }
    k0 += (l >> 4) * 8;
    short* p = dst + ((size_t)tile * 64 + l) * 8;
    for (int jj = 0; jj < 8; jj++) {
        int k = k0 + jj;
        float v = 0.f;
        if (u < H && k < H) v = src[(size_t)row * H + k];
        p[jj] = f2bf(v);
    }
}

__global__ void k_pack_fc2(const float* __restrict__ w, short* __restrict__ dst) {
    int tile = blockIdx.x;
    int kt = tile % 16, mt = tile / 16;
    int l = threadIdx.x;
    int o = mt * 16 + (l & 15);
    int k0 = kt * 32 + (l >> 4) * 8;
    short* p = dst + ((size_t)tile * 64 + l) * 8;
    for (int jj = 0; jj < 8; jj++) {
        int k = k0 + jj; float v = 0.f;
        if (o < O_OUT && k < H) v = w[(size_t)o * H + k];
        p[jj] = f2bf(v);
    }
}

__global__ void k_hin(const float* __restrict__ x, const float* __restrict__ w,
                      const float* __restrict__ bias, float* __restrict__ hin) {
    int b = blockIdx.x, o = threadIdx.x;
    float acc = 0.f;
    if (o < D_IN) {
        acc = bias[o];
        for (int k = 0; k < D_IN; k++) acc += x[b * D_IN + k] * w[o * D_IN + k];
        acc = fmaxf(acc, 0.f);
    }
    hin[b * 64 + o] = (o < D_IN) ? acc : 0.f;
}

__global__ void k_g0(const float* __restrict__ hin, const float* __restrict__ w_ih0,
                     const float* __restrict__ b_ih0, float* __restrict__ g0) {
    int b = blockIdx.x, tid = threadIdx.x;
    __shared__ float shx[D_IN];
    if (tid < D_IN) shx[tid] = hin[b * 64 + tid];
    __syncthreads();
    for (int o = tid; o < NP; o += 256) {
        float acc = 0.f;
        if (o < 3 * H) {
            acc = b_ih0[o];
            for (int k = 0; k < D_IN; k++) acc += shx[k] * w_ih0[(size_t)o * D_IN + k];
        }
        g0[(size_t)b * NP + o] = acc;
    }
}

// ---------------------------------------------------------------------------
// One wave role of phase B: R1's exact proven loop body restricted to ONE
// row-half (rowoff = 0 or 16). Single weight stream, straight unroll —
// DO NOT restructure the load/MFMA pattern (R4/R5 lesson).
// ---------------------------------------------------------------------------
template <int NK>
__device__ __forceinline__ void role_half(const short* __restrict__ stg, int abase, int ak0,
                                          int rowoff,
                                          const short* __restrict__ wg0,
                                          const short* __restrict__ wg1,
                                          const short* __restrict__ wg2,
                                          float* __restrict__ dr, float* __restrict__ dz,
                                          float* __restrict__ dn, int lane) {
    const int arow = rowoff + (lane & 15);
    const int acol = (lane >> 4) * 8;
    f32x4 ar0 = {0.f,0.f,0.f,0.f};
    f32x4 az0 = {0.f,0.f,0.f,0.f};
    f32x4 an0 = {0.f,0.f,0.f,0.f};
    #pragma unroll
    for (int kk = 0; kk < NK; kk++) {
        int ak = ak0 + kk;
        s16x8 x0 = *(const s16x8*)&stg[abase + arow * SSTR + ak * 32 + acol];
        s16x8 br = *(const s16x8*)&wg0[(size_t)kk * 512 + lane * 8];
        s16x8 bz = *(const s16x8*)&wg1[(size_t)kk * 512 + lane * 8];
        s16x8 bn = *(const s16x8*)&wg2[(size_t)kk * 512 + lane * 8];
        ar0 = __builtin_amdgcn_mfma_f32_16x16x32_bf16(x0, br, ar0, 0, 0, 0);
        az0 = __builtin_amdgcn_mfma_f32_16x16x32_bf16(x0, bz, az0, 0, 0, 0);
        an0 = __builtin_amdgcn_mfma_f32_16x16x32_bf16(x0, bn, an0, 0, 0, 0);
    }
    int ul = lane & 15, mrow = rowoff + (lane >> 4) * 4;
    #pragma unroll
    for (int r = 0; r < 4; r++) {
        dr[(mrow + r) * 18 + ul] = ar0[r];
        dz[(mrow + r) * 18 + ul] = az0[r];
        dn[(mrow + r) * 18 + ul] = an0[r];
    }
}

// ---------------------------------------------------------------------------
// Persistent pipelined GRU — R16: R1 (best, 2252us) with each of the 6 wave
// roles split into TWO row-half waves => 768 threads, 12 waves/block,
// 3 waves/SIMD (2x TLP) while keeping grid=256, 1 block/CU (no co-residency
// assumption — R6's deadlock lesson). LDS layout, slots, phase C math,
// staging and barrier are byte-for-byte R1. Pair p=wave>>1 maps to R1's
// wave p role; half=wave&1 selects rows 0-15 / 16-31 (same weight stream,
// shared lines hit L1/L2; disjoint rows of the same hgl slot).
// ---------------------------------------------------------------------------
__global__ __launch_bounds__(768, 3)   // 3 waves/EU => VGPR cap ~168; 12 waves resident
void k_gru_persist(const short* __restrict__ packW0,
                   const short* __restrict__ packW1,
                   const short* __restrict__ packW2,
                   const float* __restrict__ g0,
                   const float* __restrict__ b_hh0,
                   const float* __restrict__ b_ih1, const float* __restrict__ b_hh1,
                   const float* __restrict__ b_ih2, const float* __restrict__ b_hh2,
                   short* __restrict__ ysA,    // layer0 out at t, overwritten by layer2 at t (step t+2)
                   short* __restrict__ ysB,    // layer1 out
                   unsigned* __restrict__ cnt) {
    const int bg   = blockIdx.x & 7;      // XCD-local batch group (dispatch round-robins XCDs)
    const int j    = blockIdx.x >> 3;     // j-slice 0..31 within the XCD
    const int b0   = bg * 32;
    const int tid  = threadIdx.x;
    const int lane = tid & 63;
    const int wave = tid >> 6;            // 0..11
    const int pair = wave >> 1;           // 0..5 == R1's wave role
    const int half = wave & 1;            // row-half 0/1
    const s16x8 z8 = {0, 0, 0, 0, 0, 0, 0, 0};

    extern __shared__ __align__(16) char smem[];
    short* stg = (short*)smem;                         // SA/SB/SC
    float* hgl = (float*)(smem + LDS_STAGE * 2);       // [18][HSTR]
    float* sg0 = hgl + 18 * HSTR;                      // [32*48]
    float* sbb = sg0 + 32 * 48;                        // [3][4][16]

    // ---- wave role parameters (uniform per wave; loop-invariant)
    int abase, ak0, slot0;
    const short* wg0; const short* wg1; const short* wg2;
    {
        const short* wpk; int KT, kt0;
        switch (pair) {
            case 0:  wpk = packW0; KT = 16; kt0 = 0;  abase = LDS_SA; ak0 = 0; slot0 = 0;  break;
            case 1:  wpk = packW0; KT = 16; kt0 = 8;  abase = LDS_SA; ak0 = 8; slot0 = 1;  break;
            case 2:  wpk = packW1; KT = 32; kt0 = 0;  abase = LDS_SA; ak0 = 0; slot0 = 6;  break;
            case 3:  wpk = packW1; KT = 32; kt0 = 16; abase = LDS_SB; ak0 = 0; slot0 = 7;  break;
            case 4:  wpk = packW2; KT = 32; kt0 = 0;  abase = LDS_SB; ak0 = 0; slot0 = 12; break;
            default: wpk = packW2; KT = 32; kt0 = 16; abase = LDS_SC; ak0 = 0; slot0 = 13; break;
        }
        wg0 = wpk + ((size_t)((j * 3 + 0) * KT + kt0) * 512);
        wg1 = wpk + ((size_t)((j * 3 + 1) * KT + kt0) * 512);
        wg2 = wpk + ((size_t)((j * 3 + 2) * KT + kt0) * 512);
    }
    float* dr = hgl + (size_t)slot0 * HSTR;
    float* dz = hgl + (size_t)(slot0 + 2) * HSTR;
    float* dn = hgl + (size_t)(slot0 + 4) * HSTR;
    const int rowoff = half * 16;

    // ---- layer0 x-gate constants (g0 + b_hh0 folded for r,z)
    for (int c = tid; c < 32 * 48; c += 768) {
        int m = c / 48, col = c % 48;
        int g = col >> 4, ul = col & 15;
        int u = j * 16 + ul;
        float v = 0.f;
        if (u < H) {
            v = g0[(size_t)(b0 + m) * NP + g * H + u];
            if (g == 0) v += b_hh0[u];
            else if (g == 1) v += b_hh0[H + u];
        }
        sg0[m * 48 + col] = v;
    }
    if (tid < 48) {
        int l = tid >> 4, ul = tid & 15, u = j * 16 + ul;
        float br = 0.f, bz = 0.f, bxn = 0.f, bhn = 0.f;
        if (u < H) {
            if (l == 0) bhn = b_hh0[2 * H + u];
            else {
                const float* bi = (l == 1) ? b_ih1 : b_ih2;
                const float* bh = (l == 1) ? b_hh1 : b_hh2;
                br = bi[u] + bh[u]; bz = bi[H + u] + bh[H + u];
                bxn = bi[2 * H + u]; bhn = bh[2 * H + u];
            }
        }
        sbb[(l * 4 + 0) * 16 + ul] = br;  sbb[(l * 4 + 1) * 16 + ul] = bz;
        sbb[(l * 4 + 2) * 16 + ul] = bxn; sbb[(l * 4 + 3) * 16 + ul] = bhn;
    }
    __syncthreads();

    unsigned* mycnt = cnt + bg * 32;   // 128B-strided counters

    for (int s = 0; s < T_STEPS + 2; ++s) {
        const bool hasL0 = (s < T_STEPS);
        const bool hasL1 = (s >= 1 && s <= T_STEPS);
        const bool hasL2 = (s >= 2);
        const short* ysAm1 = ysA + (size_t)(s - 1) * BATCH * HP;
        const short* ysBm2 = ysB + (size_t)(s - 2) * BATCH * HP;
        const short* ysAm3 = ysA + (size_t)(s - 3) * BATCH * HP;

        // ================= PHASE A: coalesced staging of all three tiles ====
        #pragma unroll
        for (int i = 0; i < 3; i++) {
            int c = tid + i * 768;
            if (c < 2048) {
                int r = c >> 6, cc = c & 63;
                size_t goff = (size_t)(b0 + r) * HP + cc * 8;
                s16x8 va = z8, vb = z8, vc = z8;
                if (s >= 1 && s <= T_STEPS) va = *(const s16x8*)&ysAm1[goff];
                if (s >= 2)                 vb = *(const s16x8*)&ysBm2[goff];
                if (s >= 3) {
                    const ull* p = (const ull*)&ysAm3[goff];
                    union { ull q[2]; s16x8 v; } uu;
                    uu.q[0] = __hip_atomic_load(p,     __ATOMIC_RELAXED, __HIP_MEMORY_SCOPE_AGENT);
                    uu.q[1] = __hip_atomic_load(p + 1, __ATOMIC_RELAXED, __HIP_MEMORY_SCOPE_AGENT);
                    vc = uu.v;
                }
                int loff = r * SSTR + cc * 8;
                *(s16x8*)&stg[LDS_SA + loff] = va;
                *(s16x8*)&stg[LDS_SB + loff] = vb;
                *(s16x8*)&stg[LDS_SC + loff] = vc;
            }
        }
        __syncthreads();                                   // (1) tiles staged

        // ================= PHASE B: 12 row-half roles, R1 codegen ===========
        {
            const bool active = (pair < 2) ? hasL0 : ((pair < 4) ? hasL1 : hasL2);
            if (active) {
                if (pair < 2) role_half<8>(stg, abase, ak0, rowoff, wg0, wg1, wg2, dr, dz, dn, lane);
                else          role_half<16>(stg, abase, ak0, rowoff, wg0, wg1, wg2, dr, dz, dn, lane);
            }
        }
        __syncthreads();                                   // (2) hgl complete

        // ================= PHASE C: all gates (768 items / 768 threads) =====
        {
            int idx = tid;
            int which = idx >> 8, id8 = idx & 255;
            int m = id8 >> 3, pr = id8 & 7;
            int b = b0 + m;
            if (which == 0 && hasL0) {
                short* dst = ysA + (size_t)s * BATCH * HP;
                unsigned pk = 0;
                #pragma unroll
                for (int e = 0; e < 2; e++) {
                    int ul = pr * 2 + e, u = j * 16 + ul, mo = m * 18 + ul;
                    float hv = 0.f;
                    if (u < H) {
                        float hr = hgl[0 * HSTR + mo] + hgl[1 * HSTR + mo];
                        float hz = hgl[2 * HSTR + mo] + hgl[3 * HSTR + mo];
                        float hn = hgl[4 * HSTR + mo] + hgl[5 * HSTR + mo];
                        float r = sigm(sg0[m * 48 + ul] + hr);
                        float z = sigm(sg0[m * 48 + 16 + ul] + hz);
                        float n = tanh_fast(sg0[m * 48 + 32 + ul] + r * (hn + sbb[3 * 16 + ul]));
                        float hold = bf2f(stg[LDS_SA + m * SSTR + u]);
                        hv = (1.f - z) * n + z * hold;
                    }
                    pk |= ((unsigned)(unsigned short)f2bf(hv)) << (16 * e);
                }
                __hip_atomic_store((unsigned*)&dst[(size_t)b * HP + j * 16 + pr * 2], pk,
                                   __ATOMIC_RELAXED, __HIP_MEMORY_SCOPE_AGENT);
            } else if (which == 1 && hasL1) {
                short* dst = ysB + (size_t)(s - 1) * BATCH * HP;
                unsigned pk = 0;
                #pragma unroll
                for (int e = 0; e < 2; e++) {
                    int ul = pr * 2 + e, u = j * 16 + ul, mo = m * 18 + ul;
                    float hv = 0.f;
                    if (u < H) {
                        float xr = hgl[6 * HSTR + mo]  + sbb[(4 + 0) * 16 + ul];
                        float hr = hgl[7 * HSTR + mo];
                        float xz = hgl[8 * HSTR + mo]  + sbb[(4 + 1) * 16 + ul];
                        float hz = hgl[9 * HSTR + mo];
                        float xn = hgl[10 * HSTR + mo] + sbb[(4 + 2) * 16 + ul];
                        float hn = hgl[11 * HSTR + mo] + sbb[(4 + 3) * 16 + ul];
                        float r = sigm(xr + hr);
                        float z = sigm(xz + hz);
                        float n = tanh_fast(xn + r * hn);
                        float hold = bf2f(stg[LDS_SB + m * SSTR + u]);
                        hv = (1.f - z) * n + z * hold;
                    }
                    pk |= ((unsigned)(unsigned short)f2bf(hv)) << (16 * e);
                }
                __hip_atomic_store((unsigned*)&dst[(size_t)b * HP + j * 16 + pr * 2], pk,
                                   __ATOMIC_RELAXED, __HIP_MEMORY_SCOPE_AGENT);
            } else if (which == 2 && hasL2) {
                short* dst = ysA + (size_t)(s - 2) * BATCH * HP;
                unsigned pk = 0;
                #pragma unroll
                for (int e = 0; e < 2; e++) {
                    int ul = pr * 2 + e, u = j * 16 + ul, mo = m * 18 + ul;
                    float hv = 0.f;
                    if (u < H) {
                        float xr = hgl[12 * HSTR + mo] + sbb[(8 + 0) * 16 + ul];
                        float hr = hgl[13 * HSTR + mo];
                        float xz = hgl[14 * HSTR + mo] + sbb[(8 + 1) * 16 + ul];
                        float hz = hgl[15 * HSTR + mo];
                        float xn = hgl[16 * HSTR + mo] + sbb[(8 + 2) * 16 + ul];
                        float hn = hgl[17 * HSTR + mo] + sbb[(8 + 3) * 16 + ul];
                        float r = sigm(xr + hr);
                        float z = sigm(xz + hz);
                        float n = tanh_fast(xn + r * hn);
                        float hold = bf2f(stg[LDS_SC + m * SSTR + u]);
                        hv = (1.f - z) * n + z * hold;
                    }
                    pk |= ((unsigned)(unsigned short)f2bf(hv)) << (16 * e);
                }
                __hip_atomic_store((unsigned*)&dst[(size_t)b * HP + j * 16 + pr * 2], pk,
                                   __ATOMIC_RELAXED, __HIP_MEMORY_SCOPE_AGENT);
            }
        }
        __syncthreads();    // (3) every wave's stores drained at barrier

        // ---- per-bg 32-block barrier: relaxed add + relaxed poll
        if (tid == 0) {
            asm volatile("s_waitcnt vmcnt(0)" ::: "memory");
            __hip_atomic_fetch_add(mycnt, 1u, __ATOMIC_RELAXED, __HIP_MEMORY_SCOPE_AGENT);
            unsigned tgt = 32u * (unsigned)(s + 1);
            while (__hip_atomic_load(mycnt, __ATOMIC_RELAXED, __HIP_MEMORY_SCOPE_AGENT) < tgt) {}
        }
        __syncthreads();                                   // (4)
    }
}

// ---------------------------------------------------------------------------
// fc2 + transpose (reads ysA = layer2 output; fresh kernel => coherent)
// ---------------------------------------------------------------------------
__global__ __launch_bounds__(256, 1)
void k_fc2(const short* __restrict__ ys2, const short* __restrict__ fc2p,
           const float* __restrict__ fc2_b, float* __restrict__ out) {
    int b = blockIdx.x;
    int tid = threadIdx.x, lane = tid & 63, wave = tid >> 6;
    const s16x8 zf = {0, 0, 0, 0, 0, 0, 0, 0};
    for (int ntile = wave; ntile < 18; ntile += 4) {
        int tt = ntile * 16 + (lane & 15);
        s16x8 bf[16];
        for (int kt = 0; kt < 16; kt++) {
            if (tt < T_STEPS)
                bf[kt] = *(const s16x8*)&ys2[((size_t)tt * BATCH + b) * HP + kt * 32 + (lane >> 4) * 8];
            else
                bf[kt] = zf;
        }
        for (int mt = 0; mt < 5; mt++) {
            f32x4 acc = {0.f, 0.f, 0.f, 0.f};
            for (int kt = 0; kt < 16; kt++) {
                s16x8 af = *(const s16x8*)&fc2p[(((size_t)mt * 16 + kt) * 64 + lane) * 8];
                acc = __builtin_amdgcn_mfma_f32_16x16x32_bf16(af, bf[kt], acc, 0, 0, 0);
            }
            int obase = mt * 16 + (lane >> 4) * 4;
            for (int r = 0; r < 4; r++) {
                int o = obase + r;
                if (o < O_OUT && tt < T_STEPS)
                    out[((size_t)b * O_OUT + o) * T_STEPS + tt] = acc[r] + fc2_b[o];
            }
        }
    }
}

// ---------------------------------------------------------------------------
extern "C" void kernel_launch(void* const* d_in, const int* in_sizes, int n_in,
                              void* d_out, int out_size, void* d_ws, size_t ws_size,
                              hipStream_t stream) {
    const float* x     = (const float*)d_in[0];
    const float* fc1_w = (const float*)d_in[1];
    const float* fc1_b = (const float*)d_in[2];
    const float* w_ih0 = (const float*)d_in[3];
    const float* w_hh0 = (const float*)d_in[4];
    const float* b_ih0 = (const float*)d_in[5];
    const float* b_hh0 = (const float*)d_in[6];
    const float* w_ih1 = (const float*)d_in[7];
    const float* w_hh1 = (const float*)d_in[8];
    const float* b_ih1 = (const float*)d_in[9];
    const float* b_hh1 = (const float*)d_in[10];
    const float* w_ih2 = (const float*)d_in[11];
    const float* w_hh2 = (const float*)d_in[12];
    const float* b_ih2 = (const float*)d_in[13];
    const float* b_hh2 = (const float*)d_in[14];
    const float* fc2_w = (const float*)d_in[15];
    const float* fc2_b = (const float*)d_in[16];
    float* out = (float*)d_out;

    char* p = (char*)d_ws;
    auto alloc = [&](size_t bytes) {
        char* r = p; p += (bytes + 255) & ~(size_t)255; return r;
    };
    short* packW0 = (short*)alloc((size_t)32 * 3 * 16 * 64 * 8 * 2);
    short* packW1 = (short*)alloc((size_t)32 * 3 * 32 * 64 * 8 * 2);
    short* packW2 = (short*)alloc((size_t)32 * 3 * 32 * 64 * 8 * 2);
    short* packF  = (short*)alloc((size_t)80 * 64 * 8 * 2);
    float* hin    = (float*)alloc((size_t)BATCH * 64 * 4);
    float* g0     = (float*)alloc((size_t)BATCH * NP * 4);
    unsigned* cnt = (unsigned*)alloc(256 * 4);
    short* ysA    = (short*)alloc((size_t)T_STEPS * BATCH * HP * 2);
    short* ysB    = (short*)alloc((size_t)T_STEPS * BATCH * HP * 2);

    // opt in to >64KB dynamic LDS (host-side attribute; graph-capture safe)
    static bool attr_set = false;
    if (!attr_set) {
        (void)hipFuncSetAttribute((const void*)k_gru_persist,
                                  hipFuncAttributeMaxDynamicSharedMemorySize,
                                  DYN_LDS);
        attr_set = true;
    }

    hipMemsetAsync(cnt, 0, 256 * 4, stream);
    k_pack_gru<<<32 * 3 * 16, 64, 0, stream>>>(nullptr, w_hh0, packW0, 16);
    k_pack_gru<<<32 * 3 * 32, 64, 0, stream>>>(w_ih1, w_hh1, packW1, 32);
    k_pack_gru<<<32 * 3 * 32, 64, 0, stream>>>(w_ih2, w_hh2, packW2, 32);
    k_pack_fc2<<<80, 64, 0, stream>>>(fc2_w, packF);
    k_hin<<<BATCH, 64, 0, stream>>>(x, fc1_w, fc1_b, hin);
    k_g0<<<BATCH, 256, 0, stream>>>(hin, w_ih0, b_ih0, g0);

    k_gru_persist<<<256, 768, DYN_LDS, stream>>>(packW0, packW1, packW2, g0,
                                                 b_hh0, b_ih1, b_hh1, b_ih2, b_hh2,
                                                 ysA, ysB, cnt);

    k_fc2<<<BATCH, 256, 0, stream>>>(ysA, packF, fc2_b, out);
}